// Round 5
// baseline (64.200 us; speedup 1.0000x reference)
//
#include <hip/hip_runtime.h>
#include <hip/hip_bf16.h>
#include <math.h>

#define LSEQ   2048
#define DMODEL 256
#define NHALF  32
#define TMAX   1024                 // fallback-path truncation
#define TM2    384                  // fast-path truncation (amp ~ 4.6e-9)
#define KPAD   16
#define KROWS  (LSEQ + 2*KPAD)
#define TT     16
#define CTL_N  1232

typedef __attribute__((ext_vector_type(8))) short short8;
typedef __attribute__((ext_vector_type(4))) float f32x4;
typedef __attribute__((ext_vector_type(4))) unsigned int u32x4;

// ---- MFMA-path geometry
#define UB_STR    2056                       // bf16 per u-row (pad 8 -> 4112B stride, conflict-free B reads)
#define UB_SHORTS (8*UB_STR)                 // 16448
#define UB_BYTES  (UB_SHORTS*2)              // 32896
#define KB8_LEN    4352                      // elements per copy (z_max read = 4119)
#define KB8_STR_B  (KB8_LEN*2 + 32)          // 8736 B: 16B-aligned, +8-word bank stagger
#define KB8_PERD   (8*KB8_LEN)               // 34816 shorts per d in global
#define SMEM_M     (UB_BYTES + 8*KB8_STR_B)  // 102784 B dynamic LDS
#define UIMG_SHORTS ((size_t)DMODEL*UB_SHORTS)
#define KB8G_SHORTS ((size_t)DMODEL*KB8_PERD)
#define WS_NEED    ((UIMG_SHORTS + KB8G_SHORTS)*2)

// ============================================================ prep kernel:
// blocks [0,256):    build k for d=blockIdx -> kb8g[d][c][z] = bf16(k[z+c-1024])
// blocks [256,512):  transpose u [B][L][D] f32 -> uimg [d][b][m] bf16
__global__ __launch_bounds__(512, 2) void s4d_prep(
    const float* __restrict__ u,
    const float* __restrict__ A_real, const float* __restrict__ A_imag,
    const float* __restrict__ C_real, const float* __restrict__ C_imag,
    unsigned short* __restrict__ uimg, unsigned short* __restrict__ kb8g)
{
    __shared__ unsigned short tr[DMODEL][66];
    __shared__ __align__(16) float ctL0[CTL_N];
    __shared__ __align__(16) float ctL1[CTL_N];
    __shared__ __align__(16) float hRe[TM2];
    __shared__ __align__(16) float hImE[TM2/2];
    __shared__ __align__(16) float hImO[TM2/2];
    __shared__ __align__(16) unsigned short kbf[LSEQ];
    __shared__ float prm[4][NHALF];

    const int tid = threadIdx.x;

    if (blockIdx.x >= 256) {
        // ---------- transpose part (verified R3 utr, widened to 512 threads)
        const int idx = blockIdx.x - 256;
        const int m0  = (idx & 31) * 64;
        const int b   = idx >> 5;

        const int mmBase = tid >> 6;          // 0..7
        const int d4     = (tid & 63) * 4;
        #pragma unroll
        for (int it = 0; it < 8; ++it) {
            int mm = it*8 + mmBase;
            const float* src = u + ((size_t)b*LSEQ + m0 + mm)*DMODEL + d4;
            f32x4 v = *(const f32x4*)src;
            #pragma unroll
            for (int j = 0; j < 4; ++j) {
                __hip_bfloat16 hb = __float2bfloat16(v[j]);
                tr[d4+j][mm] = *(unsigned short*)&hb;
            }
        }
        __syncthreads();
        // chunk-major coalesced writes: 8 lanes -> 128B contiguous per d
        #pragma unroll
        for (int P = 0; P < 4; ++P) {
            int d = P*64 + (tid >> 3);
            int c = tid & 7;
            const unsigned short* s = &tr[d][c*8];
            u32x4 w = { *(const unsigned*)(s),   *(const unsigned*)(s+2),
                        *(const unsigned*)(s+4), *(const unsigned*)(s+6) };
            *(u32x4*)(uimg + (size_t)d*UB_SHORTS + (size_t)b*UB_STR + m0 + c*8) = w;
        }
    } else {
        // ---------- build part (verified R3 build_kb2 math; output: 8 shifted copies)
        const int d = blockIdx.x;
        if (tid < NHALF) {
            prm[0][tid] = A_real[d*NHALF + tid];
            prm[1][tid] = A_imag[d*NHALF + tid];
            prm[2][tid] = C_real[d*NHALF + tid];
            prm[3][tid] = C_imag[d*NHALF + tid];
        }
        for (int i = tid; i < 1220; i += 512) {
            int x0 = (i - 196) & 2047;
            int x1 = (i - 195) & 2047;
            float a0 = (float)(M_PI/(2.0*(double)LSEQ)) * (float)(2*x0 + 1);
            float a1 = (float)(M_PI/(2.0*(double)LSEQ)) * (float)(2*x1 + 1);
            float s0, c0, s1, c1;
            sincosf(a0, &s0, &c0);
            sincosf(a1, &s1, &c1);
            ctL0[i] = c0 / s0;
            ctL1[i] = c1 / s1;
        }
        __syncthreads();

        if (tid < TM2) {
            const int tau = tid;
            float aR = 0.f, aI = 0.f;
            for (int n = 0; n < NHALF; ++n) {
                float lr  = -expf(prm[0][n]) * 0.1f;
                float amp = expf(lr * (float)tau);
                double ph = (double)prm[1][n] * 0.1 * (double)tau;
                ph -= floor(ph * (1.0/(2.0*M_PI))) * (2.0*M_PI);
                float s, c; sincosf((float)ph, &s, &c);
                float cr = prm[2][n], ci = prm[3][n];
                aR = fmaf(amp, cr*c - ci*s, aR);
                aI = fmaf(amp, cr*s + ci*c, aI);
            }
            hRe[tau] = aR;
            if (tau & 1) hImO[tau >> 1] = aI;
            else         hImE[tau >> 1] = aI;
        }
        __syncthreads();

        {
            const int pt = tid & 1;
            const int g  = tid >> 1;
            const float* tb = pt ? ctL1 : ctL0;
            const float* hb = pt ? hImE : hImO;

            float acc0 = 0.f, acc1 = 0.f, acc2 = 0.f, acc3 = 0.f;
            int qb = 4*g + 192;
            f32x4 Wlo = *(const f32x4*)(tb + qb);
            f32x4 Whi = *(const f32x4*)(tb + qb + 4);

            #pragma unroll 4
            for (int R = 0; R < 48; ++R) {
                f32x4 hv = *(const f32x4*)(hb + 4*R);
                f32x4 Wn = *(const f32x4*)(tb + qb - 4);
                acc0 = fmaf(Wlo[3], hv[0], acc0); acc1 = fmaf(Whi[0], hv[0], acc1);
                acc2 = fmaf(Whi[1], hv[0], acc2); acc3 = fmaf(Whi[2], hv[0], acc3);
                acc0 = fmaf(Wlo[2], hv[1], acc0); acc1 = fmaf(Wlo[3], hv[1], acc1);
                acc2 = fmaf(Whi[0], hv[1], acc2); acc3 = fmaf(Whi[1], hv[1], acc3);
                acc0 = fmaf(Wlo[1], hv[2], acc0); acc1 = fmaf(Wlo[2], hv[2], acc1);
                acc2 = fmaf(Wlo[3], hv[2], acc2); acc3 = fmaf(Whi[0], hv[2], acc3);
                acc0 = fmaf(Wlo[0], hv[3], acc0); acc1 = fmaf(Wlo[1], hv[3], acc1);
                acc2 = fmaf(Wlo[2], hv[3], acc2); acc3 = fmaf(Wlo[3], hv[3], acc3);
                Whi = Wlo; Wlo = Wn; qb -= 4;
            }

            float accs[4] = {acc0, acc1, acc2, acc3};
            #pragma unroll
            for (int e = 0; e < 4; ++e) {
                int t = 8*g + 2*e + pt;
                float base = (t < TM2) ? hRe[t] : 0.f;
                float kv = base - accs[e] * (1.0f/(float)LSEQ);
                __hip_bfloat16 hbv = __float2bfloat16(kv);
                kbf[t] = *(unsigned short*)&hbv;
            }
        }
        __syncthreads();

        // write 8 shifted copies: kb8g[d][c][z] = kbf[z + c - 1024] (0 outside)
        unsigned short* od = kb8g + (size_t)d*KB8_PERD;
        #pragma unroll
        for (int c = 0; c < 8; ++c) {
            for (int i = tid; i < KB8_LEN/8; i += 512) {
                int z0 = i*8;
                unsigned short v8[8];
                #pragma unroll
                for (int e = 0; e < 8; ++e) {
                    int j = z0 + e + c - 1024;
                    v8[e] = (j >= 0 && j < LSEQ) ? kbf[j] : (unsigned short)0;
                }
                u32x4 w = { (unsigned)v8[0] | ((unsigned)v8[1] << 16),
                            (unsigned)v8[2] | ((unsigned)v8[3] << 16),
                            (unsigned)v8[4] | ((unsigned)v8[5] << 16),
                            (unsigned)v8[6] | ((unsigned)v8[7] << 16) };
                *(u32x4*)(od + c*KB8_LEN + z0) = w;
            }
        }
    }
}

// ============================================================ mfma kernel:
// per-d Toeplitz GEMM. A-fragments now single aligned ds_read_b128 from the
// 8-copy LDS image (copy c = (7-col)&7, z = x - c; byte addr ≡ 0 mod 16).
#define MF(a, b, c) __builtin_amdgcn_mfma_f32_16x16x32_bf16((a), (b), (c), 0, 0, 0)

__device__ __forceinline__ short8 loadA8(const unsigned char* sm, int addr) {
    return *(const short8*)(sm + addr);
}

__global__ __launch_bounds__(512, 1) void s4d_mfma8(
    const unsigned short* __restrict__ uimg, const unsigned short* __restrict__ kb8g,
    const float* __restrict__ Dvec, float* __restrict__ out)
{
    extern __shared__ __align__(16) unsigned char sm[];
    const int tid = threadIdx.x;
    const int Bk  = blockIdx.x;
    const int d   = ((Bk & 7) << 5) | (Bk >> 3);   // XCD-swizzle

    // ---- stage LDS
    {
        const u32x4* gu = (const u32x4*)(uimg + (size_t)d*UB_SHORTS);
        u32x4* lu = (u32x4*)sm;
        for (int i = tid; i < UB_SHORTS/8; i += 512) lu[i] = gu[i];
        const unsigned short* gk = kb8g + (size_t)d*KB8_PERD;
        #pragma unroll
        for (int c = 0; c < 8; ++c) {
            u32x4* lk = (u32x4*)(sm + UB_BYTES + c*KB8_STR_B);
            const u32x4* gc = (const u32x4*)(gk + c*KB8_LEN);
            for (int i = tid; i < KB8_LEN/8; i += 512) lk[i] = gc[i];
        }
    }
    __syncthreads();

    const int lane = tid & 63, wv = tid >> 6;
    const int h    = lane >> 4;
    const int col  = lane & 15;
    const int t0w  = wv << 8;

    // A: copy cA = (7-col) mod 8; z base = 2040 - t0w + 8h - 8*(col>=8)
    const int cA    = (col < 8) ? (7 - col) : (15 - col);
    const int zb    = 2040 - t0w + 8*h - ((col >> 3) << 3);
    const int baseA = UB_BYTES + cA*KB8_STR_B + 2*zb;
    const int laneB = (col & 7)*(UB_STR*2) + (h << 4);

    const float dv = Dvec[d];
    f32x4 acc[16];
    #pragma unroll
    for (int tt = 0; tt < 16; ++tt) acc[tt] = (f32x4){dv, dv, dv, dv};

    short8 A[16], Bb[2];
    #pragma unroll
    for (int tt = 0; tt < 16; ++tt) A[tt] = loadA8(sm, baseA - 32*tt);
    Bb[0] = *(const short8*)(sm + laneB);

    int aA = baseA + 64;
    int aB = laneB + 64;

    for (int Q = 0; Q < 8; ++Q) {
        #pragma unroll
        for (int p = 0; p < 8; ++p) {
            const short8 bcur = Bb[p & 1];
            acc[14] = MF(A[(14 - 2*p) & 15], bcur, acc[14]);
            acc[15] = MF(A[(15 - 2*p) & 15], bcur, acc[15]);
            A[(14 - 2*p) & 15] = loadA8(sm, aA);
            A[(15 - 2*p) & 15] = loadA8(sm, aA - 32);
            Bb[(p + 1) & 1]    = *(const short8*)(sm + aB);
            aA += 64; aB += 64;
            #pragma unroll
            for (int tt = 2; tt < 14; ++tt)
                acc[tt] = MF(A[(tt - 2*p) & 15], bcur, acc[tt]);
            acc[0] = MF(A[(0 - 2*p) & 15], bcur, acc[0]);
            acc[1] = MF(A[(1 - 2*p) & 15], bcur, acc[1]);
        }
    }

    if (col < 8) {
        float* ob = out + (size_t)col*LSEQ*DMODEL + d;
        #pragma unroll
        for (int tt = 0; tt < 16; ++tt) {
            int trow = t0w + tt*16 + h*4;
            float* o = ob + (size_t)trow*DMODEL;
            o[0*DMODEL] = acc[tt][0];
            o[1*DMODEL] = acc[tt][1];
            o[2*DMODEL] = acc[tt][2];
            o[3*DMODEL] = acc[tt][3];
        }
    }
}

// ============================================================ fallback (R1, verified)
__global__ __launch_bounds__(256) void s4d_build_k(
    const float* __restrict__ A_real, const float* __restrict__ A_imag,
    const float* __restrict__ C_real, const float* __restrict__ C_imag,
    float* __restrict__ kT)
{
    __shared__ float hRe[TMAX], hIm[TMAX], ct[LSEQ], prm[4][NHALF];
    const int tid = threadIdx.x;
    const int d   = blockIdx.x;
    if (tid < NHALF) {
        prm[0][tid] = A_real[d*NHALF + tid];
        prm[1][tid] = A_imag[d*NHALF + tid];
        prm[2][tid] = C_real[d*NHALF + tid];
        prm[3][tid] = C_imag[d*NHALF + tid];
    }
    #pragma unroll
    for (int r = 0; r < LSEQ/256; ++r) {
        int i = tid + 256*r;
        float ang = (float)(M_PI/(2.0*(double)LSEQ)) * (float)(2*i + 1);
        float sv, cv; sincosf(ang, &sv, &cv);
        ct[i] = cv / sv;
    }
    __syncthreads();
    for (int r = 0; r < TMAX/256; ++r) {
        int tau = tid + 256*r;
        float aR = 0.f, aI = 0.f;
        for (int n = 0; n < NHALF; ++n) {
            float lr  = -expf(prm[0][n]) * 0.1f;
            float amp = expf(lr * (float)tau);
            double ph = (double)prm[1][n] * 0.1 * (double)tau;
            ph -= floor(ph * (1.0/(2.0*M_PI))) * (2.0*M_PI);
            float sv, cv; sincosf((float)ph, &sv, &cv);
            float cr = prm[2][n], ci = prm[3][n];
            aR = fmaf(amp, cr*cv - ci*sv, aR);
            aI = fmaf(amp, cr*sv + ci*cv, aI);
        }
        hRe[tau] = aR; hIm[tau] = aI;
    }
    __syncthreads();
    float base[8], hsum[8];
    #pragma unroll
    for (int r = 0; r < 8; ++r) {
        base[r] = (r < 4) ? hRe[tid + 256*r] : 0.f;
        hsum[r] = 0.f;
    }
    const int tau0 = (tid & 1) ^ 1;
    for (int tau = tau0; tau < TMAX; tau += 2) {
        float him = hIm[tau];
        #pragma unroll
        for (int r = 0; r < 8; ++r) {
            int idx = ((tid + 256*r - tau) & (2*LSEQ - 1)) >> 1;
            hsum[r] = fmaf(ct[idx], him, hsum[r]);
        }
    }
    #pragma unroll
    for (int r = 0; r < 8; ++r) {
        int t = tid + 256*r;
        kT[(t + KPAD)*DMODEL + d] = base[r] - hsum[r] * (1.0f/(float)LSEQ);
    }
    if (tid < 2*KPAD) {
        int row = (tid < KPAD) ? tid : (LSEQ + KPAD + (tid - KPAD));
        kT[row*DMODEL + d] = 0.f;
    }
}

__global__ __launch_bounds__(256) void s4d_conv(
    const float* __restrict__ u, const float* __restrict__ Dvec,
    const float* __restrict__ kT, float* __restrict__ out)
{
    const int d  = threadIdx.x;
    const int t0 = blockIdx.x * TT;
    const int b  = blockIdx.y;
    float dvv = Dvec[d];
    float acc[TT];
    #pragma unroll
    for (int i = 0; i < TT; ++i) acc[i] = dvv;
    const float* ub   = u + (size_t)b * LSEQ * DMODEL + d;
    const float* kcol = kT + d;
    int mstart = t0 - 1024; if (mstart < 0) mstart = 0;
    int mend   = t0 + 1040; if (mend > LSEQ) mend = LSEQ;
    float kreg[31];
    {
        int jpb = mstart - t0 + 1024;
        #pragma unroll
        for (int r = 0; r < 31; ++r) kreg[r] = kcol[(jpb + r)*DMODEL];
    }
    for (int m0 = mstart; m0 < mend; m0 += TT) {
        float ureg[TT];
        #pragma unroll
        for (int mm = 0; mm < TT; ++mm) ureg[mm] = ub[(m0 + mm)*DMODEL];
        float knew[TT];
        if (m0 + TT < mend) {
            int jnb = m0 - t0 + 1024 + 31;
            #pragma unroll
            for (int r = 0; r < TT; ++r) knew[r] = kcol[(jnb + r)*DMODEL];
        } else {
            #pragma unroll
            for (int r = 0; r < TT; ++r) knew[r] = 0.f;
        }
        #pragma unroll
        for (int mm = 0; mm < TT; ++mm)
            #pragma unroll
            for (int tt = 0; tt < TT; ++tt)
                acc[tt] = fmaf(ureg[mm], kreg[mm - tt + 15], acc[tt]);
        #pragma unroll
        for (int r = 0; r < 15; ++r) kreg[r] = kreg[r + 16];
        #pragma unroll
        for (int r = 0; r < 16; ++r) kreg[15 + r] = knew[r];
    }
    float* ob = out + ((size_t)b * LSEQ + t0) * DMODEL + d;
    #pragma unroll
    for (int tt = 0; tt < TT; ++tt) ob[tt*DMODEL] = acc[tt];
}

// ============================================================ launch
extern "C" void kernel_launch(void* const* d_in, const int* in_sizes, int n_in,
                              void* d_out, int out_size, void* d_ws, size_t ws_size,
                              hipStream_t stream)
{
    const float* u  = (const float*)d_in[0];
    const float* Ar = (const float*)d_in[1];
    const float* Ai = (const float*)d_in[2];
    const float* Cr = (const float*)d_in[3];
    const float* Ci = (const float*)d_in[4];
    const float* Dv = (const float*)d_in[5];
    float* out = (float*)d_out;
    int B = in_sizes[0] / (LSEQ * DMODEL);

    if (B == 8 && ws_size >= WS_NEED) {
        unsigned short* uimg = (unsigned short*)d_ws;
        unsigned short* kb8g = uimg + UIMG_SHORTS;
        // allow >64KB dynamic LDS (idempotent, deterministic, not a stream op)
        hipFuncSetAttribute((const void*)s4d_mfma8,
                            hipFuncAttributeMaxDynamicSharedMemorySize, SMEM_M);
        s4d_prep<<<512, 512, 0, stream>>>(u, Ar, Ai, Cr, Ci, uimg, kb8g);
        s4d_mfma8<<<DMODEL, 512, SMEM_M, stream>>>(uimg, kb8g, Dv, out);
    } else {
        float* kT = (float*)d_ws;
        s4d_build_k<<<DMODEL, 256, 0, stream>>>(Ar, Ai, Cr, Ci, kT);
        s4d_conv<<<dim3(LSEQ/TT, B), 256, 0, stream>>>(u, Dv, kT, out);
    }
}

// Round 6
// 61.072 us; speedup vs baseline: 1.0512x; 1.0512x over previous
//
#include <hip/hip_runtime.h>
#include <hip/hip_bf16.h>
#include <math.h>

#define LSEQ   2048
#define DMODEL 256
#define NHALF  32
#define TMAX   1024                 // fallback-path truncation
#define TM2    384                  // fast-path truncation (amp ~ 4.6e-9)
#define KPAD   16
#define KROWS  (LSEQ + 2*KPAD)
#define TT     16
#define CTL_N  1232

typedef __attribute__((ext_vector_type(8))) short short8;
typedef __attribute__((ext_vector_type(4))) float f32x4;
typedef __attribute__((ext_vector_type(4))) unsigned int u32x4;

// ---- MFMA-path geometry (R5-verified addressing)
#define UB_STR    2056                       // bf16 per u-row
#define UB_SHORTS (8*UB_STR)                 // 16448
#define UB_BYTES  (UB_SHORTS*2)              // 32896
#define KB8_LEN    4352                      // shorts per k-copy
#define KB8_STR_B  (KB8_LEN*2 + 32)          // 8736 B, 16B-aligned + bank stagger
// dynamic-LDS layout (bytes)
#define OFF_K     UB_BYTES                   // 32896
#define OFF_CT0   (OFF_K + 8*KB8_STR_B)      // 102784
#define OFF_CT1   (OFF_CT0 + CTL_N*4)        // 107712
#define OFF_HRE   (OFF_CT1 + CTL_N*4)        // 112640
#define OFF_HIE   (OFF_HRE + TM2*4)          // 114176
#define OFF_HIO   (OFF_HIE + (TM2/2)*4)      // 114944
#define OFF_KBF   (OFF_HIO + (TM2/2)*4)      // 115712
#define OFF_PRM   (OFF_KBF + LSEQ*2)         // 119808
#define SMEM_F    (OFF_PRM + 4*NHALF*4)      // 120320
#define UIMG_SHORTS ((size_t)DMODEL*UB_SHORTS)
#define WS_NEED   (UIMG_SHORTS*2)

// ============================================================ stage 0 (R3-verified):
// u [B][L][D] f32  ->  uimg [d][b][m] bf16 (row stride UB_STR)
__global__ __launch_bounds__(256) void s4d_utr(const float* __restrict__ u,
                                               unsigned short* __restrict__ uimg)
{
    __shared__ unsigned short tr[DMODEL][66];
    const int tid = threadIdx.x;
    const int m0  = blockIdx.x * 64;
    const int b   = blockIdx.y;

    const int mmBase = tid >> 6;
    const int d4     = (tid & 63) * 4;
    for (int it = 0; it < 16; ++it) {
        int mm = it*4 + mmBase;
        const float* src = u + ((size_t)b*LSEQ + m0 + mm)*DMODEL + d4;
        f32x4 v = *(const f32x4*)src;
        #pragma unroll
        for (int j = 0; j < 4; ++j) {
            __hip_bfloat16 hb = __float2bfloat16(v[j]);
            tr[d4+j][mm] = *(unsigned short*)&hb;
        }
    }
    __syncthreads();
    #pragma unroll
    for (int P = 0; P < 8; ++P) {
        int d = P*32 + (tid >> 3);
        int c = tid & 7;
        const unsigned short* s = &tr[d][c*8];
        u32x4 w = { *(const unsigned*)(s),   *(const unsigned*)(s+2),
                    *(const unsigned*)(s+4), *(const unsigned*)(s+6) };
        *(u32x4*)(uimg + (size_t)d*UB_SHORTS + (size_t)b*UB_STR + m0 + c*8) = w;
    }
}

// ============================================================ fused kernel:
// one block per d. Early-issue u staging loads -> build k in LDS (verified
// R3 math) -> expand 8 shifted copies in LDS (verified R5 layout) -> ds_write
// staged u -> verified R5 aligned-b128 Toeplitz-MFMA loop.
#define MF(a, b, c) __builtin_amdgcn_mfma_f32_16x16x32_bf16((a), (b), (c), 0, 0, 0)

__global__ __launch_bounds__(512, 1) void s4d_fused2(
    const unsigned short* __restrict__ uimg,
    const float* __restrict__ A_real, const float* __restrict__ A_imag,
    const float* __restrict__ C_real, const float* __restrict__ C_imag,
    const float* __restrict__ Dvec, float* __restrict__ out)
{
    extern __shared__ __align__(16) unsigned char sm[];
    float* ctL0 = (float*)(sm + OFF_CT0);
    float* ctL1 = (float*)(sm + OFF_CT1);
    float* hRe  = (float*)(sm + OFF_HRE);
    float* hImE = (float*)(sm + OFF_HIE);
    float* hImO = (float*)(sm + OFF_HIO);
    unsigned short* kbf = (unsigned short*)(sm + OFF_KBF);
    float* prm  = (float*)(sm + OFF_PRM);      // [4][NHALF]

    const int tid = threadIdx.x;
    const int Bk  = blockIdx.x;
    const int d   = ((Bk & 7) << 5) | (Bk >> 3);   // XCD-swizzle

    // ---- issue u staging loads EARLY (results used after build)
    const u32x4* gu = (const u32x4*)(uimg + (size_t)d*UB_SHORTS);
    u32x4 stg[5];
    #pragma unroll
    for (int r = 0; r < 5; ++r) {
        int i = tid + 512*r;
        if (i < 2056) stg[r] = gu[i];
    }

    // ---- build phase A: params + cot tables
    if (tid < NHALF) {
        prm[0*NHALF + tid] = A_real[d*NHALF + tid];
        prm[1*NHALF + tid] = A_imag[d*NHALF + tid];
        prm[2*NHALF + tid] = C_real[d*NHALF + tid];
        prm[3*NHALF + tid] = C_imag[d*NHALF + tid];
    }
    for (int i = tid; i < 1220; i += 512) {
        int x0 = (i - 196) & 2047;
        int x1 = (i - 195) & 2047;
        float a0 = (float)(M_PI/(2.0*(double)LSEQ)) * (float)(2*x0 + 1);
        float a1 = (float)(M_PI/(2.0*(double)LSEQ)) * (float)(2*x1 + 1);
        float s0, c0, s1, c1;
        sincosf(a0, &s0, &c0);
        sincosf(a1, &s1, &c1);
        ctL0[i] = c0 / s0;
        ctL1[i] = c1 / s1;
    }
    __syncthreads();

    // ---- build phase B: 32-mode eval (verified math)
    if (tid < TM2) {
        const int tau = tid;
        float aR = 0.f, aI = 0.f;
        for (int n = 0; n < NHALF; ++n) {
            float lr  = -expf(prm[0*NHALF + n]) * 0.1f;
            float amp = expf(lr * (float)tau);
            double ph = (double)prm[1*NHALF + n] * 0.1 * (double)tau;
            ph -= floor(ph * (1.0/(2.0*M_PI))) * (2.0*M_PI);
            float s, c; sincosf((float)ph, &s, &c);
            float cr = prm[2*NHALF + n], ci = prm[3*NHALF + n];
            aR = fmaf(amp, cr*c - ci*s, aR);
            aI = fmaf(amp, cr*s + ci*c, aI);
        }
        hRe[tau] = aR;
        if (tau & 1) hImO[tau >> 1] = aI;
        else         hImE[tau >> 1] = aI;
    }
    __syncthreads();

    // ---- build phase C: register-blocked Hilbert (verified math) -> kbf bf16
    {
        const int pt = tid & 1;
        const int g  = tid >> 1;
        const float* tb = pt ? ctL1 : ctL0;
        const float* hb = pt ? hImE : hImO;

        float acc0 = 0.f, acc1 = 0.f, acc2 = 0.f, acc3 = 0.f;
        int qb = 4*g + 192;
        f32x4 Wlo = *(const f32x4*)(tb + qb);
        f32x4 Whi = *(const f32x4*)(tb + qb + 4);

        #pragma unroll 4
        for (int R = 0; R < 48; ++R) {
            f32x4 hv = *(const f32x4*)(hb + 4*R);
            f32x4 Wn = *(const f32x4*)(tb + qb - 4);
            acc0 = fmaf(Wlo[3], hv[0], acc0); acc1 = fmaf(Whi[0], hv[0], acc1);
            acc2 = fmaf(Whi[1], hv[0], acc2); acc3 = fmaf(Whi[2], hv[0], acc3);
            acc0 = fmaf(Wlo[2], hv[1], acc0); acc1 = fmaf(Wlo[3], hv[1], acc1);
            acc2 = fmaf(Whi[0], hv[1], acc2); acc3 = fmaf(Whi[1], hv[1], acc3);
            acc0 = fmaf(Wlo[1], hv[2], acc0); acc1 = fmaf(Wlo[2], hv[2], acc1);
            acc2 = fmaf(Wlo[3], hv[2], acc2); acc3 = fmaf(Whi[0], hv[2], acc3);
            acc0 = fmaf(Wlo[0], hv[3], acc0); acc1 = fmaf(Wlo[1], hv[3], acc1);
            acc2 = fmaf(Wlo[2], hv[3], acc2); acc3 = fmaf(Wlo[3], hv[3], acc3);
            Whi = Wlo; Wlo = Wn; qb -= 4;
        }

        float accs[4] = {acc0, acc1, acc2, acc3};
        #pragma unroll
        for (int e = 0; e < 4; ++e) {
            int t = 8*g + 2*e + pt;
            float base = (t < TM2) ? hRe[t] : 0.f;
            float kv = base - accs[e] * (1.0f/(float)LSEQ);
            __hip_bfloat16 hbv = __float2bfloat16(kv);
            kbf[t] = *(unsigned short*)&hbv;
        }
    }
    __syncthreads();

    // ---- expand 8 shifted k-copies into LDS (verified R5 layout) + write u
    #pragma unroll
    for (int c = 0; c < 8; ++c) {
        unsigned char* lk = sm + OFF_K + c*KB8_STR_B;
        for (int i = tid; i < KB8_LEN/8; i += 512) {
            int z0 = i*8;
            unsigned short v8[8];
            #pragma unroll
            for (int e = 0; e < 8; ++e) {
                int j = z0 + e + c - 1024;
                v8[e] = (j >= 0 && j < LSEQ) ? kbf[j] : (unsigned short)0;
            }
            u32x4 w = { (unsigned)v8[0] | ((unsigned)v8[1] << 16),
                        (unsigned)v8[2] | ((unsigned)v8[3] << 16),
                        (unsigned)v8[4] | ((unsigned)v8[5] << 16),
                        (unsigned)v8[6] | ((unsigned)v8[7] << 16) };
            *(u32x4*)(lk + z0*2) = w;
        }
    }
    #pragma unroll
    for (int r = 0; r < 5; ++r) {
        int i = tid + 512*r;
        if (i < 2056) *(u32x4*)(sm + i*16) = stg[r];
    }
    __syncthreads();

    // ---- main loop (byte-identical to verified R5 s4d_mfma8)
    const int lane = tid & 63, wv = tid >> 6;
    const int h    = lane >> 4;
    const int col  = lane & 15;
    const int t0w  = wv << 8;

    const int cA    = (col < 8) ? (7 - col) : (15 - col);
    const int zb    = 2040 - t0w + 8*h - ((col >> 3) << 3);
    const int baseA = OFF_K + cA*KB8_STR_B + 2*zb;
    const int laneB = (col & 7)*(UB_STR*2) + (h << 4);

    const float dv = Dvec[d];
    f32x4 acc[16];
    #pragma unroll
    for (int tt = 0; tt < 16; ++tt) acc[tt] = (f32x4){dv, dv, dv, dv};

    short8 A[16], Bb[2];
    #pragma unroll
    for (int tt = 0; tt < 16; ++tt) A[tt] = *(const short8*)(sm + baseA - 32*tt);
    Bb[0] = *(const short8*)(sm + laneB);

    int aA = baseA + 64;
    int aB = laneB + 64;

    for (int Q = 0; Q < 8; ++Q) {
        #pragma unroll
        for (int p = 0; p < 8; ++p) {
            const short8 bcur = Bb[p & 1];
            acc[14] = MF(A[(14 - 2*p) & 15], bcur, acc[14]);
            acc[15] = MF(A[(15 - 2*p) & 15], bcur, acc[15]);
            A[(14 - 2*p) & 15] = *(const short8*)(sm + aA);
            A[(15 - 2*p) & 15] = *(const short8*)(sm + aA - 32);
            Bb[(p + 1) & 1]    = *(const short8*)(sm + aB);
            aA += 64; aB += 64;
            #pragma unroll
            for (int tt = 2; tt < 14; ++tt)
                acc[tt] = MF(A[(tt - 2*p) & 15], bcur, acc[tt]);
            acc[0] = MF(A[(0 - 2*p) & 15], bcur, acc[0]);
            acc[1] = MF(A[(1 - 2*p) & 15], bcur, acc[1]);
        }
    }

    if (col < 8) {
        float* ob = out + (size_t)col*LSEQ*DMODEL + d;
        #pragma unroll
        for (int tt = 0; tt < 16; ++tt) {
            int trow = t0w + tt*16 + h*4;
            float* o = ob + (size_t)trow*DMODEL;
            o[0*DMODEL] = acc[tt][0];
            o[1*DMODEL] = acc[tt][1];
            o[2*DMODEL] = acc[tt][2];
            o[3*DMODEL] = acc[tt][3];
        }
    }
}

// ============================================================ fallback (R1, verified)
__global__ __launch_bounds__(256) void s4d_build_k(
    const float* __restrict__ A_real, const float* __restrict__ A_imag,
    const float* __restrict__ C_real, const float* __restrict__ C_imag,
    float* __restrict__ kT)
{
    __shared__ float hRe[TMAX], hIm[TMAX], ct[LSEQ], prm[4][NHALF];
    const int tid = threadIdx.x;
    const int d   = blockIdx.x;
    if (tid < NHALF) {
        prm[0][tid] = A_real[d*NHALF + tid];
        prm[1][tid] = A_imag[d*NHALF + tid];
        prm[2][tid] = C_real[d*NHALF + tid];
        prm[3][tid] = C_imag[d*NHALF + tid];
    }
    #pragma unroll
    for (int r = 0; r < LSEQ/256; ++r) {
        int i = tid + 256*r;
        float ang = (float)(M_PI/(2.0*(double)LSEQ)) * (float)(2*i + 1);
        float sv, cv; sincosf(ang, &sv, &cv);
        ct[i] = cv / sv;
    }
    __syncthreads();
    for (int r = 0; r < TMAX/256; ++r) {
        int tau = tid + 256*r;
        float aR = 0.f, aI = 0.f;
        for (int n = 0; n < NHALF; ++n) {
            float lr  = -expf(prm[0][n]) * 0.1f;
            float amp = expf(lr * (float)tau);
            double ph = (double)prm[1][n] * 0.1 * (double)tau;
            ph -= floor(ph * (1.0/(2.0*M_PI))) * (2.0*M_PI);
            float sv, cv; sincosf((float)ph, &sv, &cv);
            float cr = prm[2][n], ci = prm[3][n];
            aR = fmaf(amp, cr*cv - ci*sv, aR);
            aI = fmaf(amp, cr*sv + ci*cv, aI);
        }
        hRe[tau] = aR; hIm[tau] = aI;
    }
    __syncthreads();
    float base[8], hsum[8];
    #pragma unroll
    for (int r = 0; r < 8; ++r) {
        base[r] = (r < 4) ? hRe[tid + 256*r] : 0.f;
        hsum[r] = 0.f;
    }
    const int tau0 = (tid & 1) ^ 1;
    for (int tau = tau0; tau < TMAX; tau += 2) {
        float him = hIm[tau];
        #pragma unroll
        for (int r = 0; r < 8; ++r) {
            int idx = ((tid + 256*r - tau) & (2*LSEQ - 1)) >> 1;
            hsum[r] = fmaf(ct[idx], him, hsum[r]);
        }
    }
    #pragma unroll
    for (int r = 0; r < 8; ++r) {
        int t = tid + 256*r;
        kT[(t + KPAD)*DMODEL + d] = base[r] - hsum[r] * (1.0f/(float)LSEQ);
    }
    if (tid < 2*KPAD) {
        int row = (tid < KPAD) ? tid : (LSEQ + KPAD + (tid - KPAD));
        kT[row*DMODEL + d] = 0.f;
    }
}

__global__ __launch_bounds__(256) void s4d_conv(
    const float* __restrict__ u, const float* __restrict__ Dvec,
    const float* __restrict__ kT, float* __restrict__ out)
{
    const int d  = threadIdx.x;
    const int t0 = blockIdx.x * TT;
    const int b  = blockIdx.y;
    float dvv = Dvec[d];
    float acc[TT];
    #pragma unroll
    for (int i = 0; i < TT; ++i) acc[i] = dvv;
    const float* ub   = u + (size_t)b * LSEQ * DMODEL + d;
    const float* kcol = kT + d;
    int mstart = t0 - 1024; if (mstart < 0) mstart = 0;
    int mend   = t0 + 1040; if (mend > LSEQ) mend = LSEQ;
    float kreg[31];
    {
        int jpb = mstart - t0 + 1024;
        #pragma unroll
        for (int r = 0; r < 31; ++r) kreg[r] = kcol[(jpb + r)*DMODEL];
    }
    for (int m0 = mstart; m0 < mend; m0 += TT) {
        float ureg[TT];
        #pragma unroll
        for (int mm = 0; mm < TT; ++mm) ureg[mm] = ub[(m0 + mm)*DMODEL];
        float knew[TT];
        if (m0 + TT < mend) {
            int jnb = m0 - t0 + 1024 + 31;
            #pragma unroll
            for (int r = 0; r < TT; ++r) knew[r] = kcol[(jnb + r)*DMODEL];
        } else {
            #pragma unroll
            for (int r = 0; r < TT; ++r) knew[r] = 0.f;
        }
        #pragma unroll
        for (int mm = 0; mm < TT; ++mm)
            #pragma unroll
            for (int tt = 0; tt < TT; ++tt)
                acc[tt] = fmaf(ureg[mm], kreg[mm - tt + 15], acc[tt]);
        #pragma unroll
        for (int r = 0; r < 15; ++r) kreg[r] = kreg[r + 16];
        #pragma unroll
        for (int r = 0; r < 16; ++r) kreg[15 + r] = knew[r];
    }
    float* ob = out + ((size_t)b * LSEQ + t0) * DMODEL + d;
    #pragma unroll
    for (int tt = 0; tt < TT; ++tt) ob[tt*DMODEL] = acc[tt];
}

// ============================================================ launch
extern "C" void kernel_launch(void* const* d_in, const int* in_sizes, int n_in,
                              void* d_out, int out_size, void* d_ws, size_t ws_size,
                              hipStream_t stream)
{
    const float* u  = (const float*)d_in[0];
    const float* Ar = (const float*)d_in[1];
    const float* Ai = (const float*)d_in[2];
    const float* Cr = (const float*)d_in[3];
    const float* Ci = (const float*)d_in[4];
    const float* Dv = (const float*)d_in[5];
    float* out = (float*)d_out;
    int B = in_sizes[0] / (LSEQ * DMODEL);

    if (B == 8 && ws_size >= WS_NEED) {
        unsigned short* uimg = (unsigned short*)d_ws;
        hipFuncSetAttribute((const void*)s4d_fused2,
                            hipFuncAttributeMaxDynamicSharedMemorySize, SMEM_F);
        s4d_utr<<<dim3(LSEQ/64, 8), 256, 0, stream>>>(u, uimg);
        s4d_fused2<<<DMODEL, 512, SMEM_F, stream>>>(uimg, Ar, Ai, Cr, Ci, Dv, out);
    } else {
        float* kT = (float*)d_ws;
        s4d_build_k<<<DMODEL, 256, 0, stream>>>(Ar, Ai, Cr, Ci, kT);
        s4d_conv<<<dim3(LSEQ/TT, B), 256, 0, stream>>>(u, Dv, kT, out);
    }
}

// Round 7
// 54.999 us; speedup vs baseline: 1.1673x; 1.1104x over previous
//
#include <hip/hip_runtime.h>
#include <hip/hip_bf16.h>
#include <math.h>

#define LSEQ   2048
#define DMODEL 256
#define NHALF  32
#define TMAX   1024                 // fallback-path truncation
#define TM2    384                  // fast-path truncation
#define KPAD   16
#define KROWS  (LSEQ + 2*KPAD)
#define TT     16

typedef __attribute__((ext_vector_type(8))) short short8;
typedef __attribute__((ext_vector_type(4))) float f32x4;
typedef __attribute__((ext_vector_type(4))) unsigned int u32x4;

// ---- MFMA-path geometry (R5/R6-verified addressing)
#define UB_STR    2056
#define UB_SHORTS (8*UB_STR)                 // 16448
#define UB_BYTES  (UB_SHORTS*2)              // 32896
#define KB8_LEN   4352
#define KB8_STR_B (KB8_LEN*2 + 32)           // 8736
// dynamic-LDS layout (bytes)
#define OFF_K     UB_BYTES                   // 32896 ; slot c at OFF_K + c*KB8_STR_B
#define OFF_CT0   (OFF_K + 8*KB8_STR_B)      // 102784
#define OFF_CT1   (OFF_CT0 + 1232*4)         // 107712
#define OFF_HRE   (OFF_CT0 + 2464*4)         // 112640
#define OFF_HIE   (OFF_HRE + TM2*4)          // 114176
#define OFF_HIO   (OFF_HIE + (TM2/2)*4)      // 114944
#define OFF_P     (OFF_HIO + (TM2/2)*4)      // 115712  (16 rows x 68 f32)
#define OFF_Q     (OFF_P + 16*68*4)          // 120064  (24 rows x 68 f32)
#define OFF_C     (OFF_Q + 24*68*4)          // 126592  (32 cplx)
#define SMEM_F2   (OFF_C + 256)              // 126848
#define UIMG_SHORTS ((size_t)DMODEL*UB_SHORTS)
#define WS_CT_OFF   (UIMG_SHORTS*2)          // bytes; ct0[1232]||ct1[1232] f32
#define WS_NEED2    (WS_CT_OFF + 2464*4)

// ============================================================ ct tables (d-independent, once):
__global__ __launch_bounds__(512) void s4d_ctk(float* __restrict__ wct)
{
    int i = blockIdx.x*512 + threadIdx.x;
    if (i < 1220) {
        int x0 = (i - 196) & 2047;
        int x1 = (i - 195) & 2047;
        float a0 = (float)(M_PI/(2.0*(double)LSEQ)) * (float)(2*x0 + 1);
        float a1 = (float)(M_PI/(2.0*(double)LSEQ)) * (float)(2*x1 + 1);
        float s0, c0, s1, c1;
        sincosf(a0, &s0, &c0);
        sincosf(a1, &s1, &c1);
        wct[i] = c0 / s0;
        wct[1232 + i] = c1 / s1;
    } else if (i < 1232) {
        wct[i] = 0.f; wct[1232 + i] = 0.f;
    }
}

// ============================================================ stage 0 (R3-verified):
__global__ __launch_bounds__(256) void s4d_utr(const float* __restrict__ u,
                                               unsigned short* __restrict__ uimg)
{
    __shared__ unsigned short tr[DMODEL][66];
    const int tid = threadIdx.x;
    const int m0  = blockIdx.x * 64;
    const int b   = blockIdx.y;

    const int mmBase = tid >> 6;
    const int d4     = (tid & 63) * 4;
    for (int it = 0; it < 16; ++it) {
        int mm = it*4 + mmBase;
        const float* src = u + ((size_t)b*LSEQ + m0 + mm)*DMODEL + d4;
        f32x4 v = *(const f32x4*)src;
        #pragma unroll
        for (int j = 0; j < 4; ++j) {
            __hip_bfloat16 hb = __float2bfloat16(v[j]);
            tr[d4+j][mm] = *(unsigned short*)&hb;
        }
    }
    __syncthreads();
    #pragma unroll
    for (int P = 0; P < 8; ++P) {
        int d = P*32 + (tid >> 3);
        int c = tid & 7;
        const unsigned short* s = &tr[d][c*8];
        u32x4 w = { *(const unsigned*)(s),   *(const unsigned*)(s+2),
                    *(const unsigned*)(s+4), *(const unsigned*)(s+6) };
        *(u32x4*)(uimg + (size_t)d*UB_SHORTS + (size_t)b*UB_STR + m0 + c*8) = w;
    }
}

// ============================================================ fused kernel
#define MF(a, b, c) __builtin_amdgcn_mfma_f32_16x16x32_bf16((a), (b), (c), 0, 0, 0)

__global__ __launch_bounds__(512, 1) void s4d_fused3(
    const unsigned short* __restrict__ uimg, const float* __restrict__ wct,
    const float* __restrict__ A_real, const float* __restrict__ A_imag,
    const float* __restrict__ C_real, const float* __restrict__ C_imag,
    const float* __restrict__ Dvec, float* __restrict__ out)
{
    extern __shared__ __align__(16) unsigned char sm[];
    float* hRe  = (float*)(sm + OFF_HRE);
    float* hImE = (float*)(sm + OFF_HIE);
    float* hImO = (float*)(sm + OFF_HIO);

    const int tid = threadIdx.x;
    const int Bk  = blockIdx.x;
    const int d   = ((Bk & 7) << 5) | (Bk >> 3);   // XCD-swizzle

    // ---- issue global loads early
    const u32x4* gu = (const u32x4*)(uimg + (size_t)d*UB_SHORTS);
    u32x4 stg[5];
    #pragma unroll
    for (int r = 0; r < 5; ++r) {
        int i = tid + 512*r;
        if (i < 2056) stg[r] = gu[i];
    }
    const f32x4* gct = (const f32x4*)wct;
    f32x4 ctg[2];
    ctg[0] = gct[tid];                       // groups 0..511 (of 616)
    if (tid < 104) ctg[1] = gct[tid + 512];

    // ---- phase 0: power tables (lanes 0-31) + zero slot0 pads (threads 64-353)
    if (tid < 32) {
        const int n = tid;
        float ar = A_real[d*NHALF + n], ai = A_imag[d*NHALF + n];
        float cr = C_real[d*NHALF + n], ci = C_imag[d*NHALF + n];
        float amp = expf(-0.1f * expf(ar));
        float sn, cs; sincosf(0.1f * ai, &sn, &cs);
        float Adr = amp*cs, Adi = amp*sn;            // A_disc
        float* Pp = (float*)(sm + OFF_P);
        float* Qp = (float*)(sm + OFF_Q);
        float* Cp = (float*)(sm + OFF_C);
        float pr = 1.f, pi = 0.f;
        Pp[n*2] = pr; Pp[n*2 + 1] = pi;
        #pragma unroll
        for (int i = 1; i < 16; ++i) {
            float nr = pr*Adr - pi*Adi;
            float ni = pr*Adi + pi*Adr;
            pr = nr; pi = ni;
            Pp[i*68 + n*2] = pr; Pp[i*68 + n*2 + 1] = pi;
        }
        float a16r = pr*Adr - pi*Adi;                // A^16
        float a16i = pr*Adi + pi*Adr;
        float qr = 1.f, qi = 0.f;
        Qp[n*2] = qr; Qp[n*2 + 1] = qi;
        #pragma unroll
        for (int j = 1; j < 24; ++j) {
            float nr = qr*a16r - qi*a16i;
            float ni = qr*a16i + qi*a16r;
            qr = nr; qi = ni;
            Qp[j*68 + n*2] = qr; Qp[j*68 + n*2 + 1] = qi;
        }
        Cp[n*2] = cr; Cp[n*2 + 1] = ci;
    }
    {
        int zi = tid - 64;                 // zero slot0 shorts [0,1024) and [3072,4368)
        if (zi >= 0 && zi < 290) {
            int off = (zi < 128) ? zi*16 : 6144 + (zi - 128)*16;
            *(u32x4*)(sm + OFF_K + off) = (u32x4){0,0,0,0};
        }
    }
    __syncthreads();

    // ---- phase B: write ct + u to LDS; h[tau] = sum_n C_n P[tau&15] Q[tau>>4]
    *(f32x4*)(sm + OFF_CT0 + tid*16) = ctg[0];
    if (tid < 104) *(f32x4*)(sm + OFF_CT0 + (tid + 512)*16) = ctg[1];
    #pragma unroll
    for (int r = 0; r < 5; ++r) {
        int i = tid + 512*r;
        if (i < 2056) *(u32x4*)(sm + i*16) = stg[r];
    }
    if (tid < TM2) {
        const int tau = tid, ii = tau & 15, jj = tau >> 4;
        const float* Pr = (const float*)(sm + OFF_P) + ii*68;
        const float* Qr = (const float*)(sm + OFF_Q) + jj*68;
        const float* Cc = (const float*)(sm + OFF_C);
        float aR = 0.f, aI = 0.f;
        #pragma unroll 4
        for (int n = 0; n < 32; n += 2) {
            f32x4 p = *(const f32x4*)(Pr + 2*n);
            f32x4 q = *(const f32x4*)(Qr + 2*n);
            f32x4 c = *(const f32x4*)(Cc + 2*n);
            float w0r = p[0]*q[0] - p[1]*q[1];
            float w0i = p[0]*q[1] + p[1]*q[0];
            aR = fmaf(c[0], w0r, aR); aR = fmaf(-c[1], w0i, aR);
            aI = fmaf(c[0], w0i, aI); aI = fmaf( c[1], w0r, aI);
            float w1r = p[2]*q[2] - p[3]*q[3];
            float w1i = p[2]*q[3] + p[3]*q[2];
            aR = fmaf(c[2], w1r, aR); aR = fmaf(-c[3], w1i, aR);
            aI = fmaf(c[2], w1i, aI); aI = fmaf( c[3], w1r, aI);
        }
        hRe[tau] = aR;
        if (tau & 1) hImO[tau >> 1] = aI;
        else         hImE[tau >> 1] = aI;
    }
    __syncthreads();

    // ---- phase C: register-blocked Hilbert (verified R3 math) -> k into slot0 [+1024]
    {
        const int pt = tid & 1;
        const int g  = tid >> 1;
        const float* tb = (const float*)(sm + (pt ? OFF_CT1 : OFF_CT0));
        const float* hb = (const float*)(sm + (pt ? OFF_HIE : OFF_HIO));

        float acc0 = 0.f, acc1 = 0.f, acc2 = 0.f, acc3 = 0.f;
        int qb = 4*g + 192;
        f32x4 Wlo = *(const f32x4*)(tb + qb);
        f32x4 Whi = *(const f32x4*)(tb + qb + 4);

        #pragma unroll 4
        for (int R = 0; R < 48; ++R) {
            f32x4 hv = *(const f32x4*)(hb + 4*R);
            f32x4 Wn = *(const f32x4*)(tb + qb - 4);
            acc0 = fmaf(Wlo[3], hv[0], acc0); acc1 = fmaf(Whi[0], hv[0], acc1);
            acc2 = fmaf(Whi[1], hv[0], acc2); acc3 = fmaf(Whi[2], hv[0], acc3);
            acc0 = fmaf(Wlo[2], hv[1], acc0); acc1 = fmaf(Wlo[3], hv[1], acc1);
            acc2 = fmaf(Whi[0], hv[1], acc2); acc3 = fmaf(Whi[1], hv[1], acc3);
            acc0 = fmaf(Wlo[1], hv[2], acc0); acc1 = fmaf(Wlo[2], hv[2], acc1);
            acc2 = fmaf(Wlo[3], hv[2], acc2); acc3 = fmaf(Whi[0], hv[2], acc3);
            acc0 = fmaf(Wlo[0], hv[3], acc0); acc1 = fmaf(Wlo[1], hv[3], acc1);
            acc2 = fmaf(Wlo[2], hv[3], acc2); acc3 = fmaf(Wlo[3], hv[3], acc3);
            Whi = Wlo; Wlo = Wn; qb -= 4;
        }

        unsigned short* slot0 = (unsigned short*)(sm + OFF_K);
        float accs[4] = {acc0, acc1, acc2, acc3};
        #pragma unroll
        for (int e = 0; e < 4; ++e) {
            int t = 8*g + 2*e + pt;
            float base = (t < TM2) ? hRe[t] : 0.f;
            float kv = base - accs[e] * (1.0f/(float)LSEQ);
            __hip_bfloat16 hbv = __float2bfloat16(kv);
            slot0[1024 + t] = *(unsigned short*)&hbv;
        }
    }
    __syncthreads();

    // ---- expand: slots 1..7 from slot0 via aligned b128 + register shifts
    {
        const unsigned short* s0p = (const unsigned short*)(sm + OFF_K);
        for (int i = tid; i < KB8_LEN/8; i += 512) {
            int z0 = i*8;
            u32x4 va = *(const u32x4*)(s0p + z0);
            u32x4 vb = *(const u32x4*)(s0p + z0 + 8);
            unsigned src[8] = { va[0], va[1], va[2], va[3],
                                vb[0], vb[1], vb[2], vb[3] };
            #pragma unroll
            for (int c = 1; c < 8; ++c) {
                u32x4 w;
                if ((c & 1) == 0) {
                    int q = c >> 1;
                    w = (u32x4){ src[q], src[q+1], src[q+2], src[q+3] };
                } else {
                    int q = (c - 1) >> 1;
                    w = (u32x4){ (src[q]   >> 16) | (src[q+1] << 16),
                                 (src[q+1] >> 16) | (src[q+2] << 16),
                                 (src[q+2] >> 16) | (src[q+3] << 16),
                                 (src[q+3] >> 16) | (src[q+4] << 16) };
                }
                *(u32x4*)(sm + OFF_K + c*KB8_STR_B + z0*2) = w;
            }
        }
    }
    __syncthreads();

    // ---- main loop (byte-identical to verified R5/R6)
    const int lane = tid & 63, wv = tid >> 6;
    const int h    = lane >> 4;
    const int col  = lane & 15;
    const int t0w  = wv << 8;

    const int cA    = (col < 8) ? (7 - col) : (15 - col);
    const int zb    = 2040 - t0w + 8*h - ((col >> 3) << 3);
    const int baseA = OFF_K + cA*KB8_STR_B + 2*zb;
    const int laneB = (col & 7)*(UB_STR*2) + (h << 4);

    const float dv = Dvec[d];
    f32x4 acc[16];
    #pragma unroll
    for (int tt = 0; tt < 16; ++tt) acc[tt] = (f32x4){dv, dv, dv, dv};

    short8 A[16], Bb[2];
    #pragma unroll
    for (int tt = 0; tt < 16; ++tt) A[tt] = *(const short8*)(sm + baseA - 32*tt);
    Bb[0] = *(const short8*)(sm + laneB);

    int aA = baseA + 64;
    int aB = laneB + 64;

    for (int Q = 0; Q < 8; ++Q) {
        #pragma unroll
        for (int p = 0; p < 8; ++p) {
            const short8 bcur = Bb[p & 1];
            acc[14] = MF(A[(14 - 2*p) & 15], bcur, acc[14]);
            acc[15] = MF(A[(15 - 2*p) & 15], bcur, acc[15]);
            A[(14 - 2*p) & 15] = *(const short8*)(sm + aA);
            A[(15 - 2*p) & 15] = *(const short8*)(sm + aA - 32);
            Bb[(p + 1) & 1]    = *(const short8*)(sm + aB);
            aA += 64; aB += 64;
            #pragma unroll
            for (int tt = 2; tt < 14; ++tt)
                acc[tt] = MF(A[(tt - 2*p) & 15], bcur, acc[tt]);
            acc[0] = MF(A[(0 - 2*p) & 15], bcur, acc[0]);
            acc[1] = MF(A[(1 - 2*p) & 15], bcur, acc[1]);
        }
    }

    if (col < 8) {
        float* ob = out + (size_t)col*LSEQ*DMODEL + d;
        #pragma unroll
        for (int tt = 0; tt < 16; ++tt) {
            int trow = t0w + tt*16 + h*4;
            float* o = ob + (size_t)trow*DMODEL;
            o[0*DMODEL] = acc[tt][0];
            o[1*DMODEL] = acc[tt][1];
            o[2*DMODEL] = acc[tt][2];
            o[3*DMODEL] = acc[tt][3];
        }
    }
}

// ============================================================ fallback (R1, verified)
__global__ __launch_bounds__(256) void s4d_build_k(
    const float* __restrict__ A_real, const float* __restrict__ A_imag,
    const float* __restrict__ C_real, const float* __restrict__ C_imag,
    float* __restrict__ kT)
{
    __shared__ float hRe[TMAX], hIm[TMAX], ct[LSEQ], prm[4][NHALF];
    const int tid = threadIdx.x;
    const int d   = blockIdx.x;
    if (tid < NHALF) {
        prm[0][tid] = A_real[d*NHALF + tid];
        prm[1][tid] = A_imag[d*NHALF + tid];
        prm[2][tid] = C_real[d*NHALF + tid];
        prm[3][tid] = C_imag[d*NHALF + tid];
    }
    #pragma unroll
    for (int r = 0; r < LSEQ/256; ++r) {
        int i = tid + 256*r;
        float ang = (float)(M_PI/(2.0*(double)LSEQ)) * (float)(2*i + 1);
        float sv, cv; sincosf(ang, &sv, &cv);
        ct[i] = cv / sv;
    }
    __syncthreads();
    for (int r = 0; r < TMAX/256; ++r) {
        int tau = tid + 256*r;
        float aR = 0.f, aI = 0.f;
        for (int n = 0; n < NHALF; ++n) {
            float lr  = -expf(prm[0][n]) * 0.1f;
            float amp = expf(lr * (float)tau);
            double ph = (double)prm[1][n] * 0.1 * (double)tau;
            ph -= floor(ph * (1.0/(2.0*M_PI))) * (2.0*M_PI);
            float sv, cv; sincosf((float)ph, &sv, &cv);
            float cr = prm[2][n], ci = prm[3][n];
            aR = fmaf(amp, cr*cv - ci*sv, aR);
            aI = fmaf(amp, cr*sv + ci*cv, aI);
        }
        hRe[tau] = aR; hIm[tau] = aI;
    }
    __syncthreads();
    float base[8], hsum[8];
    #pragma unroll
    for (int r = 0; r < 8; ++r) {
        base[r] = (r < 4) ? hRe[tid + 256*r] : 0.f;
        hsum[r] = 0.f;
    }
    const int tau0 = (tid & 1) ^ 1;
    for (int tau = tau0; tau < TMAX; tau += 2) {
        float him = hIm[tau];
        #pragma unroll
        for (int r = 0; r < 8; ++r) {
            int idx = ((tid + 256*r - tau) & (2*LSEQ - 1)) >> 1;
            hsum[r] = fmaf(ct[idx], him, hsum[r]);
        }
    }
    #pragma unroll
    for (int r = 0; r < 8; ++r) {
        int t = tid + 256*r;
        kT[(t + KPAD)*DMODEL + d] = base[r] - hsum[r] * (1.0f/(float)LSEQ);
    }
    if (tid < 2*KPAD) {
        int row = (tid < KPAD) ? tid : (LSEQ + KPAD + (tid - KPAD));
        kT[row*DMODEL + d] = 0.f;
    }
}

__global__ __launch_bounds__(256) void s4d_conv(
    const float* __restrict__ u, const float* __restrict__ Dvec,
    const float* __restrict__ kT, float* __restrict__ out)
{
    const int d  = threadIdx.x;
    const int t0 = blockIdx.x * TT;
    const int b  = blockIdx.y;
    float dvv = Dvec[d];
    float acc[TT];
    #pragma unroll
    for (int i = 0; i < TT; ++i) acc[i] = dvv;
    const float* ub   = u + (size_t)b * LSEQ * DMODEL + d;
    const float* kcol = kT + d;
    int mstart = t0 - 1024; if (mstart < 0) mstart = 0;
    int mend   = t0 + 1040; if (mend > LSEQ) mend = LSEQ;
    float kreg[31];
    {
        int jpb = mstart - t0 + 1024;
        #pragma unroll
        for (int r = 0; r < 31; ++r) kreg[r] = kcol[(jpb + r)*DMODEL];
    }
    for (int m0 = mstart; m0 < mend; m0 += TT) {
        float ureg[TT];
        #pragma unroll
        for (int mm = 0; mm < TT; ++mm) ureg[mm] = ub[(m0 + mm)*DMODEL];
        float knew[TT];
        if (m0 + TT < mend) {
            int jnb = m0 - t0 + 1024 + 31;
            #pragma unroll
            for (int r = 0; r < TT; ++r) knew[r] = kcol[(jnb + r)*DMODEL];
        } else {
            #pragma unroll
            for (int r = 0; r < TT; ++r) knew[r] = 0.f;
        }
        #pragma unroll
        for (int mm = 0; mm < TT; ++mm)
            #pragma unroll
            for (int tt = 0; tt < TT; ++tt)
                acc[tt] = fmaf(ureg[mm], kreg[mm - tt + 15], acc[tt]);
        #pragma unroll
        for (int r = 0; r < 15; ++r) kreg[r] = kreg[r + 16];
        #pragma unroll
        for (int r = 0; r < 16; ++r) kreg[15 + r] = knew[r];
    }
    float* ob = out + ((size_t)b * LSEQ + t0) * DMODEL + d;
    #pragma unroll
    for (int tt = 0; tt < TT; ++tt) ob[tt*DMODEL] = acc[tt];
}

// ============================================================ launch
extern "C" void kernel_launch(void* const* d_in, const int* in_sizes, int n_in,
                              void* d_out, int out_size, void* d_ws, size_t ws_size,
                              hipStream_t stream)
{
    const float* u  = (const float*)d_in[0];
    const float* Ar = (const float*)d_in[1];
    const float* Ai = (const float*)d_in[2];
    const float* Cr = (const float*)d_in[3];
    const float* Ci = (const float*)d_in[4];
    const float* Dv = (const float*)d_in[5];
    float* out = (float*)d_out;
    int B = in_sizes[0] / (LSEQ * DMODEL);

    if (B == 8 && ws_size >= WS_NEED2) {
        unsigned short* uimg = (unsigned short*)d_ws;
        float* wct = (float*)((unsigned char*)d_ws + WS_CT_OFF);
        hipFuncSetAttribute((const void*)s4d_fused3,
                            hipFuncAttributeMaxDynamicSharedMemorySize, SMEM_F2);
        s4d_ctk<<<3, 512, 0, stream>>>(wct);
        s4d_utr<<<dim3(LSEQ/64, 8), 256, 0, stream>>>(u, uimg);
        s4d_fused3<<<DMODEL, 512, SMEM_F2, stream>>>(uimg, wct, Ar, Ai, Cr, Ci, Dv, out);
    } else {
        float* kT = (float*)d_ws;
        s4d_build_k<<<DMODEL, 256, 0, stream>>>(Ar, Ai, Cr, Ci, kT);
        s4d_conv<<<dim3(LSEQ/TT, B), 256, 0, stream>>>(u, Dv, kT, out);
    }
}

// Round 8
// 50.551 us; speedup vs baseline: 1.2700x; 1.0880x over previous
//
#include <hip/hip_runtime.h>
#include <hip/hip_bf16.h>
#include <math.h>

#define LSEQ   2048
#define DMODEL 256
#define NHALF  32
#define TMAX   1024                 // fallback-path truncation
#define TM2    384                  // fast-path truncation
#define KPAD   16
#define KROWS  (LSEQ + 2*KPAD)
#define TT     16

typedef __attribute__((ext_vector_type(8))) short short8;
typedef __attribute__((ext_vector_type(4))) float f32x4;
typedef __attribute__((ext_vector_type(4))) unsigned int u32x4;

// ---- MFMA-path geometry
#define UB_STR    2056
#define UB_SHORTS (8*UB_STR)                 // 16448
#define UB_BYTES  (UB_SHORTS*2)              // 32896
#define KB8_LEN   4352
// 8720 = 16 (mod 128): copy index advances exactly ONE 16B bank-slot per copy
// -> the 8-lane subgroups of every A ds_read_b128 cover 8 distinct bank-quads
// (8736 was ≡32 -> cols (c, c+4) collided -> 2-way conflict on every A-read).
#define KB8_STR_B 8720
// dynamic-LDS layout (bytes)
#define OFF_K     UB_BYTES                   // 32896 ; slot c at OFF_K + c*KB8_STR_B
#define OFF_CT0   (OFF_K + 8*KB8_STR_B)      // 102656
#define OFF_CT1   (OFF_CT0 + 1232*4)
#define OFF_HRE   (OFF_CT0 + 2464*4)
#define OFF_HIE   (OFF_HRE + TM2*4)
#define OFF_HIO   (OFF_HIE + (TM2/2)*4)
#define OFF_P     (OFF_HIO + (TM2/2)*4)      // 16 rows x 68 f32
#define OFF_Q     (OFF_P + 16*68*4)          // 24 rows x 68 f32
#define OFF_C     (OFF_Q + 24*68*4)          // 32 cplx
#define SMEM_F2   (OFF_C + 256)              // 126720
#define UIMG_SHORTS ((size_t)DMODEL*UB_SHORTS)
#define WS_CT_OFF   (UIMG_SHORTS*2)          // bytes; ct0[1232]||ct1[1232] f32
#define WS_NEED2    (WS_CT_OFF + 2464*4)

// ============================================================ stage 0 (R3-verified)
// + folded-in d-independent cot tables (blocks (0..4, 0))
__global__ __launch_bounds__(256) void s4d_utr(const float* __restrict__ u,
                                               unsigned short* __restrict__ uimg,
                                               float* __restrict__ wct)
{
    __shared__ unsigned short tr[DMODEL][66];
    const int tid = threadIdx.x;
    const int m0  = blockIdx.x * 64;
    const int b   = blockIdx.y;

    const int mmBase = tid >> 6;
    const int d4     = (tid & 63) * 4;
    for (int it = 0; it < 16; ++it) {
        int mm = it*4 + mmBase;
        const float* src = u + ((size_t)b*LSEQ + m0 + mm)*DMODEL + d4;
        f32x4 v = *(const f32x4*)src;
        #pragma unroll
        for (int j = 0; j < 4; ++j) {
            __hip_bfloat16 hb = __float2bfloat16(v[j]);
            tr[d4+j][mm] = *(unsigned short*)&hb;
        }
    }
    __syncthreads();
    #pragma unroll
    for (int P = 0; P < 8; ++P) {
        int d = P*32 + (tid >> 3);
        int c = tid & 7;
        const unsigned short* s = &tr[d][c*8];
        u32x4 w = { *(const unsigned*)(s),   *(const unsigned*)(s+2),
                    *(const unsigned*)(s+4), *(const unsigned*)(s+6) };
        *(u32x4*)(uimg + (size_t)d*UB_SHORTS + (size_t)b*UB_STR + m0 + c*8) = w;
    }
    // folded ct-table build (d-independent)
    if (blockIdx.y == 0 && blockIdx.x < 5) {
        int i = blockIdx.x*256 + tid;
        if (i < 1220) {
            int x0 = (i - 196) & 2047;
            int x1 = (i - 195) & 2047;
            float a0 = (float)(M_PI/(2.0*(double)LSEQ)) * (float)(2*x0 + 1);
            float a1 = (float)(M_PI/(2.0*(double)LSEQ)) * (float)(2*x1 + 1);
            float s0, c0, s1, c1;
            sincosf(a0, &s0, &c0);
            sincosf(a1, &s1, &c1);
            wct[i] = c0 / s0;
            wct[1232 + i] = c1 / s1;
        } else if (i < 1232) {
            wct[i] = 0.f; wct[1232 + i] = 0.f;
        }
    }
}

// ============================================================ fused kernel
#define MF(a, b, c) __builtin_amdgcn_mfma_f32_16x16x32_bf16((a), (b), (c), 0, 0, 0)

__global__ __launch_bounds__(512, 1) void s4d_fused3(
    const unsigned short* __restrict__ uimg, const float* __restrict__ wct,
    const float* __restrict__ A_real, const float* __restrict__ A_imag,
    const float* __restrict__ C_real, const float* __restrict__ C_imag,
    const float* __restrict__ Dvec, float* __restrict__ out)
{
    extern __shared__ __align__(16) unsigned char sm[];
    float* hRe  = (float*)(sm + OFF_HRE);
    float* hImE = (float*)(sm + OFF_HIE);
    float* hImO = (float*)(sm + OFF_HIO);

    const int tid = threadIdx.x;
    const int Bk  = blockIdx.x;
    const int d   = ((Bk & 7) << 5) | (Bk >> 3);   // XCD-swizzle

    // ---- issue global loads early
    const u32x4* gu = (const u32x4*)(uimg + (size_t)d*UB_SHORTS);
    u32x4 stg[5];
    #pragma unroll
    for (int r = 0; r < 5; ++r) {
        int i = tid + 512*r;
        if (i < 2056) stg[r] = gu[i];
    }
    const f32x4* gct = (const f32x4*)wct;
    f32x4 ctg[2];
    ctg[0] = gct[tid];                       // groups 0..511 (of 616)
    if (tid < 104) ctg[1] = gct[tid + 512];

    // ---- phase 0: power tables (lanes 0-31) + zero slot0 pads
    if (tid < 32) {
        const int n = tid;
        float ar = A_real[d*NHALF + n], ai = A_imag[d*NHALF + n];
        float cr = C_real[d*NHALF + n], ci = C_imag[d*NHALF + n];
        float amp = expf(-0.1f * expf(ar));
        float sn, cs; sincosf(0.1f * ai, &sn, &cs);
        float Adr = amp*cs, Adi = amp*sn;            // A_disc
        float* Pp = (float*)(sm + OFF_P);
        float* Qp = (float*)(sm + OFF_Q);
        float* Cp = (float*)(sm + OFF_C);
        float pr = 1.f, pi = 0.f;
        Pp[n*2] = pr; Pp[n*2 + 1] = pi;
        #pragma unroll
        for (int i = 1; i < 16; ++i) {
            float nr = pr*Adr - pi*Adi;
            float ni = pr*Adi + pi*Adr;
            pr = nr; pi = ni;
            Pp[i*68 + n*2] = pr; Pp[i*68 + n*2 + 1] = pi;
        }
        float a16r = pr*Adr - pi*Adi;                // A^16
        float a16i = pr*Adi + pi*Adr;
        float qr = 1.f, qi = 0.f;
        Qp[n*2] = qr; Qp[n*2 + 1] = qi;
        #pragma unroll
        for (int j = 1; j < 24; ++j) {
            float nr = qr*a16r - qi*a16i;
            float ni = qr*a16i + qi*a16r;
            qr = nr; qi = ni;
            Qp[j*68 + n*2] = qr; Qp[j*68 + n*2 + 1] = qi;
        }
        Cp[n*2] = cr; Cp[n*2 + 1] = ci;
    }
    {
        int zi = tid - 64;                 // zero slot0 shorts [0,1024) and [3072,4368)
        if (zi >= 0 && zi < 290) {
            int off = (zi < 128) ? zi*16 : 6144 + (zi - 128)*16;
            *(u32x4*)(sm + OFF_K + off) = (u32x4){0,0,0,0};
        }
    }
    __syncthreads();

    // ---- phase B: write ct + u to LDS; h[tau] = sum_n C_n P[tau&15] Q[tau>>4]
    *(f32x4*)(sm + OFF_CT0 + tid*16) = ctg[0];
    if (tid < 104) *(f32x4*)(sm + OFF_CT0 + (tid + 512)*16) = ctg[1];
    #pragma unroll
    for (int r = 0; r < 5; ++r) {
        int i = tid + 512*r;
        if (i < 2056) *(u32x4*)(sm + i*16) = stg[r];
    }
    if (tid < TM2) {
        const int tau = tid, ii = tau & 15, jj = tau >> 4;
        const float* Pr = (const float*)(sm + OFF_P) + ii*68;
        const float* Qr = (const float*)(sm + OFF_Q) + jj*68;
        const float* Cc = (const float*)(sm + OFF_C);
        float aR = 0.f, aI = 0.f;
        #pragma unroll 4
        for (int n = 0; n < 32; n += 2) {
            f32x4 p = *(const f32x4*)(Pr + 2*n);
            f32x4 q = *(const f32x4*)(Qr + 2*n);
            f32x4 c = *(const f32x4*)(Cc + 2*n);
            float w0r = p[0]*q[0] - p[1]*q[1];
            float w0i = p[0]*q[1] + p[1]*q[0];
            aR = fmaf(c[0], w0r, aR); aR = fmaf(-c[1], w0i, aR);
            aI = fmaf(c[0], w0i, aI); aI = fmaf( c[1], w0r, aI);
            float w1r = p[2]*q[2] - p[3]*q[3];
            float w1i = p[2]*q[3] + p[3]*q[2];
            aR = fmaf(c[2], w1r, aR); aR = fmaf(-c[3], w1i, aR);
            aI = fmaf(c[2], w1i, aI); aI = fmaf( c[3], w1r, aI);
        }
        hRe[tau] = aR;
        if (tau & 1) hImO[tau >> 1] = aI;
        else         hImE[tau >> 1] = aI;
    }
    __syncthreads();

    // ---- phase C: register-blocked Hilbert (verified R3 math) -> k into slot0 [+1024]
    {
        const int pt = tid & 1;
        const int g  = tid >> 1;
        const float* tb = (const float*)(sm + (pt ? OFF_CT1 : OFF_CT0));
        const float* hb = (const float*)(sm + (pt ? OFF_HIE : OFF_HIO));

        float acc0 = 0.f, acc1 = 0.f, acc2 = 0.f, acc3 = 0.f;
        int qb = 4*g + 192;
        f32x4 Wlo = *(const f32x4*)(tb + qb);
        f32x4 Whi = *(const f32x4*)(tb + qb + 4);

        #pragma unroll 4
        for (int R = 0; R < 48; ++R) {
            f32x4 hv = *(const f32x4*)(hb + 4*R);
            f32x4 Wn = *(const f32x4*)(tb + qb - 4);
            acc0 = fmaf(Wlo[3], hv[0], acc0); acc1 = fmaf(Whi[0], hv[0], acc1);
            acc2 = fmaf(Whi[1], hv[0], acc2); acc3 = fmaf(Whi[2], hv[0], acc3);
            acc0 = fmaf(Wlo[2], hv[1], acc0); acc1 = fmaf(Wlo[3], hv[1], acc1);
            acc2 = fmaf(Whi[0], hv[1], acc2); acc3 = fmaf(Whi[1], hv[1], acc3);
            acc0 = fmaf(Wlo[1], hv[2], acc0); acc1 = fmaf(Wlo[2], hv[2], acc1);
            acc2 = fmaf(Wlo[3], hv[2], acc2); acc3 = fmaf(Whi[0], hv[2], acc3);
            acc0 = fmaf(Wlo[0], hv[3], acc0); acc1 = fmaf(Wlo[1], hv[3], acc1);
            acc2 = fmaf(Wlo[2], hv[3], acc2); acc3 = fmaf(Wlo[3], hv[3], acc3);
            Whi = Wlo; Wlo = Wn; qb -= 4;
        }

        unsigned short* slot0 = (unsigned short*)(sm + OFF_K);
        float accs[4] = {acc0, acc1, acc2, acc3};
        #pragma unroll
        for (int e = 0; e < 4; ++e) {
            int t = 8*g + 2*e + pt;
            float base = (t < TM2) ? hRe[t] : 0.f;
            float kv = base - accs[e] * (1.0f/(float)LSEQ);
            __hip_bfloat16 hbv = __float2bfloat16(kv);
            slot0[1024 + t] = *(unsigned short*)&hbv;
        }
    }
    __syncthreads();

    // ---- expand: slots 1..7 from slot0 via aligned b128 + register shifts
    {
        const unsigned short* s0p = (const unsigned short*)(sm + OFF_K);
        for (int i = tid; i < KB8_LEN/8; i += 512) {
            int z0 = i*8;
            u32x4 va = *(const u32x4*)(s0p + z0);
            u32x4 vb = *(const u32x4*)(s0p + z0 + 8);
            unsigned src[8] = { va[0], va[1], va[2], va[3],
                                vb[0], vb[1], vb[2], vb[3] };
            #pragma unroll
            for (int c = 1; c < 8; ++c) {
                u32x4 w;
                if ((c & 1) == 0) {
                    int q = c >> 1;
                    w = (u32x4){ src[q], src[q+1], src[q+2], src[q+3] };
                } else {
                    int q = (c - 1) >> 1;
                    w = (u32x4){ (src[q]   >> 16) | (src[q+1] << 16),
                                 (src[q+1] >> 16) | (src[q+2] << 16),
                                 (src[q+2] >> 16) | (src[q+3] << 16),
                                 (src[q+3] >> 16) | (src[q+4] << 16) };
                }
                *(u32x4*)(sm + OFF_K + c*KB8_STR_B + z0*2) = w;
            }
        }
    }
    __syncthreads();

    // ---- main loop (R5/R6-verified addressing; only the copy stride changed)
    const int lane = tid & 63, wv = tid >> 6;
    const int h    = lane >> 4;
    const int col  = lane & 15;
    const int t0w  = wv << 8;

    const int cA    = (col < 8) ? (7 - col) : (15 - col);
    const int zb    = 2040 - t0w + 8*h - ((col >> 3) << 3);
    const int baseA = OFF_K + cA*KB8_STR_B + 2*zb;
    const int laneB = (col & 7)*(UB_STR*2) + (h << 4);

    const float dv = Dvec[d];
    f32x4 acc[16];
    #pragma unroll
    for (int tt = 0; tt < 16; ++tt) acc[tt] = (f32x4){dv, dv, dv, dv};

    short8 A[16], Bb[2];
    #pragma unroll
    for (int tt = 0; tt < 16; ++tt) A[tt] = *(const short8*)(sm + baseA - 32*tt);
    Bb[0] = *(const short8*)(sm + laneB);

    int aA = baseA + 64;
    int aB = laneB + 64;

    for (int Q = 0; Q < 8; ++Q) {
        #pragma unroll
        for (int p = 0; p < 8; ++p) {
            const short8 bcur = Bb[p & 1];
            acc[14] = MF(A[(14 - 2*p) & 15], bcur, acc[14]);
            acc[15] = MF(A[(15 - 2*p) & 15], bcur, acc[15]);
            A[(14 - 2*p) & 15] = *(const short8*)(sm + aA);
            A[(15 - 2*p) & 15] = *(const short8*)(sm + aA - 32);
            Bb[(p + 1) & 1]    = *(const short8*)(sm + aB);
            aA += 64; aB += 64;
            #pragma unroll
            for (int tt = 2; tt < 14; ++tt)
                acc[tt] = MF(A[(tt - 2*p) & 15], bcur, acc[tt]);
            acc[0] = MF(A[(0 - 2*p) & 15], bcur, acc[0]);
            acc[1] = MF(A[(1 - 2*p) & 15], bcur, acc[1]);
        }
    }

    if (col < 8) {
        float* ob = out + (size_t)col*LSEQ*DMODEL + d;
        #pragma unroll
        for (int tt = 0; tt < 16; ++tt) {
            int trow = t0w + tt*16 + h*4;
            float* o = ob + (size_t)trow*DMODEL;
            o[0*DMODEL] = acc[tt][0];
            o[1*DMODEL] = acc[tt][1];
            o[2*DMODEL] = acc[tt][2];
            o[3*DMODEL] = acc[tt][3];
        }
    }
}

// ============================================================ fallback (R1, verified)
__global__ __launch_bounds__(256) void s4d_build_k(
    const float* __restrict__ A_real, const float* __restrict__ A_imag,
    const float* __restrict__ C_real, const float* __restrict__ C_imag,
    float* __restrict__ kT)
{
    __shared__ float hRe[TMAX], hIm[TMAX], ct[LSEQ], prm[4][NHALF];
    const int tid = threadIdx.x;
    const int d   = blockIdx.x;
    if (tid < NHALF) {
        prm[0][tid] = A_real[d*NHALF + tid];
        prm[1][tid] = A_imag[d*NHALF + tid];
        prm[2][tid] = C_real[d*NHALF + tid];
        prm[3][tid] = C_imag[d*NHALF + tid];
    }
    #pragma unroll
    for (int r = 0; r < LSEQ/256; ++r) {
        int i = tid + 256*r;
        float ang = (float)(M_PI/(2.0*(double)LSEQ)) * (float)(2*i + 1);
        float sv, cv; sincosf(ang, &sv, &cv);
        ct[i] = cv / sv;
    }
    __syncthreads();
    for (int r = 0; r < TMAX/256; ++r) {
        int tau = tid + 256*r;
        float aR = 0.f, aI = 0.f;
        for (int n = 0; n < NHALF; ++n) {
            float lr  = -expf(prm[0][n]) * 0.1f;
            float amp = expf(lr * (float)tau);
            double ph = (double)prm[1][n] * 0.1 * (double)tau;
            ph -= floor(ph * (1.0/(2.0*M_PI))) * (2.0*M_PI);
            float sv, cv; sincosf((float)ph, &sv, &cv);
            float cr = prm[2][n], ci = prm[3][n];
            aR = fmaf(amp, cr*cv - ci*sv, aR);
            aI = fmaf(amp, cr*sv + ci*cv, aI);
        }
        hRe[tau] = aR; hIm[tau] = aI;
    }
    __syncthreads();
    float base[8], hsum[8];
    #pragma unroll
    for (int r = 0; r < 8; ++r) {
        base[r] = (r < 4) ? hRe[tid + 256*r] : 0.f;
        hsum[r] = 0.f;
    }
    const int tau0 = (tid & 1) ^ 1;
    for (int tau = tau0; tau < TMAX; tau += 2) {
        float him = hIm[tau];
        #pragma unroll
        for (int r = 0; r < 8; ++r) {
            int idx = ((tid + 256*r - tau) & (2*LSEQ - 1)) >> 1;
            hsum[r] = fmaf(ct[idx], him, hsum[r]);
        }
    }
    #pragma unroll
    for (int r = 0; r < 8; ++r) {
        int t = tid + 256*r;
        kT[(t + KPAD)*DMODEL + d] = base[r] - hsum[r] * (1.0f/(float)LSEQ);
    }
    if (tid < 2*KPAD) {
        int row = (tid < KPAD) ? tid : (LSEQ + KPAD + (tid - KPAD));
        kT[row*DMODEL + d] = 0.f;
    }
}

__global__ __launch_bounds__(256) void s4d_conv(
    const float* __restrict__ u, const float* __restrict__ Dvec,
    const float* __restrict__ kT, float* __restrict__ out)
{
    const int d  = threadIdx.x;
    const int t0 = blockIdx.x * TT;
    const int b  = blockIdx.y;
    float dvv = Dvec[d];
    float acc[TT];
    #pragma unroll
    for (int i = 0; i < TT; ++i) acc[i] = dvv;
    const float* ub   = u + (size_t)b * LSEQ * DMODEL + d;
    const float* kcol = kT + d;
    int mstart = t0 - 1024; if (mstart < 0) mstart = 0;
    int mend   = t0 + 1040; if (mend > LSEQ) mend = LSEQ;
    float kreg[31];
    {
        int jpb = mstart - t0 + 1024;
        #pragma unroll
        for (int r = 0; r < 31; ++r) kreg[r] = kcol[(jpb + r)*DMODEL];
    }
    for (int m0 = mstart; m0 < mend; m0 += TT) {
        float ureg[TT];
        #pragma unroll
        for (int mm = 0; mm < TT; ++mm) ureg[mm] = ub[(m0 + mm)*DMODEL];
        float knew[TT];
        if (m0 + TT < mend) {
            int jnb = m0 - t0 + 1024 + 31;
            #pragma unroll
            for (int r = 0; r < TT; ++r) knew[r] = kcol[(jnb + r)*DMODEL];
        } else {
            #pragma unroll
            for (int r = 0; r < TT; ++r) knew[r] = 0.f;
        }
        #pragma unroll
        for (int mm = 0; mm < TT; ++mm)
            #pragma unroll
            for (int tt = 0; tt < TT; ++tt)
                acc[tt] = fmaf(ureg[mm], kreg[mm - tt + 15], acc[tt]);
        #pragma unroll
        for (int r = 0; r < 15; ++r) kreg[r] = kreg[r + 16];
        #pragma unroll
        for (int r = 0; r < 16; ++r) kreg[15 + r] = knew[r];
    }
    float* ob = out + ((size_t)b * LSEQ + t0) * DMODEL + d;
    #pragma unroll
    for (int tt = 0; tt < TT; ++tt) ob[tt*DMODEL] = acc[tt];
}

// ============================================================ launch
extern "C" void kernel_launch(void* const* d_in, const int* in_sizes, int n_in,
                              void* d_out, int out_size, void* d_ws, size_t ws_size,
                              hipStream_t stream)
{
    const float* u  = (const float*)d_in[0];
    const float* Ar = (const float*)d_in[1];
    const float* Ai = (const float*)d_in[2];
    const float* Cr = (const float*)d_in[3];
    const float* Ci = (const float*)d_in[4];
    const float* Dv = (const float*)d_in[5];
    float* out = (float*)d_out;
    int B = in_sizes[0] / (LSEQ * DMODEL);

    if (B == 8 && ws_size >= WS_NEED2) {
        unsigned short* uimg = (unsigned short*)d_ws;
        float* wct = (float*)((unsigned char*)d_ws + WS_CT_OFF);
        hipFuncSetAttribute((const void*)s4d_fused3,
                            hipFuncAttributeMaxDynamicSharedMemorySize, SMEM_F2);
        s4d_utr<<<dim3(LSEQ/64, 8), 256, 0, stream>>>(u, uimg, wct);
        s4d_fused3<<<DMODEL, 512, SMEM_F2, stream>>>(uimg, wct, Ar, Ai, Cr, Ci, Dv, out);
    } else {
        float* kT = (float*)d_ws;
        s4d_build_k<<<DMODEL, 256, 0, stream>>>(Ar, Ai, Cr, Ci, kT);
        s4d_conv<<<dim3(LSEQ/TT, B), 256, 0, stream>>>(u, Dv, kT, out);
    }
}

// Round 9
// 47.103 us; speedup vs baseline: 1.3630x; 1.0732x over previous
//
#include <hip/hip_runtime.h>
#include <hip/hip_bf16.h>
#include <math.h>

#define LSEQ   2048
#define DMODEL 256
#define NHALF  32
#define TMAX   1024                 // fallback-path truncation
#define TM2    384                  // fast-path truncation
#define KPAD   16
#define KROWS  (LSEQ + 2*KPAD)
#define TT     16

typedef __attribute__((ext_vector_type(8))) short short8;
typedef __attribute__((ext_vector_type(4))) float f32x4;
typedef __attribute__((ext_vector_type(4))) unsigned int u32x4;

// ---- hi-packed MFMA geometry -------------------------------------------
// u rows: 32 zero lead + 2048 data + 40 zero tail = 2120 shorts (stride 4240B ≡ 16 mod 128)
#define U3STR   2120
#define U3SH    (8*U3STR)                 // 16960 shorts per d
#define U3BYTES (U3SH*2)                  // 33920
// k slots: 32-short guard + 4352 payload (+ zero tail to 4400); stride 8848B ≡ 16 mod 128
#define KSLOT_STR 8848
#define OFF_K    U3BYTES                  // slot c at OFF_K + c*KSLOT_STR
#define SMEM_F3  (OFF_K + 8*KSLOT_STR)    // 104704
// scratch overlaid on slots 1..7 (they are written only in the expand phase)
#define OFF_SCR  (OFF_K + KSLOT_STR)      // 42768
#define OFF_CT0  OFF_SCR
#define OFF_CT1  (OFF_CT0 + 1232*4)
#define OFF_HRE  (OFF_CT1 + 1232*4)
#define OFF_HIE  (OFF_HRE + TM2*4)
#define OFF_HIO  (OFF_HIE + (TM2/2)*4)
#define OFF_P    (OFF_HIO + (TM2/2)*4)    // 16 rows x 68 f32
#define OFF_Q    (OFF_P + 16*68*4)        // 24 rows x 68 f32
#define OFF_C    (OFF_Q + 24*68*4)        // 32 cplx
#define UIMG_SHORTS ((size_t)DMODEL*U3SH)
#define WS_CT_OFF   (UIMG_SHORTS*2)
#define WS_NEED2    (WS_CT_OFF + 2464*4)

// ============================================================ stage 0:
// u [B][L][D] f32 -> uimg [d][b][32+m] bf16 (row 2120, zero pads) + folded ct tables
__global__ __launch_bounds__(256) void s4d_utr(const float* __restrict__ u,
                                               unsigned short* __restrict__ uimg,
                                               float* __restrict__ wct)
{
    __shared__ unsigned short tr[DMODEL][66];
    const int tid = threadIdx.x;
    const int m0  = blockIdx.x * 64;
    const int b   = blockIdx.y;

    const int mmBase = tid >> 6;
    const int d4     = (tid & 63) * 4;
    for (int it = 0; it < 16; ++it) {
        int mm = it*4 + mmBase;
        const float* src = u + ((size_t)b*LSEQ + m0 + mm)*DMODEL + d4;
        f32x4 v = *(const f32x4*)src;
        #pragma unroll
        for (int j = 0; j < 4; ++j) {
            __hip_bfloat16 hb = __float2bfloat16(v[j]);
            tr[d4+j][mm] = *(unsigned short*)&hb;
        }
    }
    __syncthreads();
    #pragma unroll
    for (int P = 0; P < 8; ++P) {
        int d = P*32 + (tid >> 3);
        int c = tid & 7;
        const unsigned short* s = &tr[d][c*8];
        u32x4 w = { *(const unsigned*)(s),   *(const unsigned*)(s+2),
                    *(const unsigned*)(s+4), *(const unsigned*)(s+6) };
        *(u32x4*)(uimg + (size_t)d*U3SH + (size_t)b*U3STR + 32 + m0 + c*8) = w;
    }
    // zero pads: lead 32 shorts (block x==0), tail 40 shorts (block x==31)
    if (blockIdx.x == 0) {
        int d = tid;
        #pragma unroll
        for (int c = 0; c < 4; ++c)
            *(u32x4*)(uimg + (size_t)d*U3SH + (size_t)b*U3STR + c*8) = (u32x4){0,0,0,0};
    } else if (blockIdx.x == 31) {
        int d = tid;
        #pragma unroll
        for (int c = 0; c < 5; ++c)
            *(u32x4*)(uimg + (size_t)d*U3SH + (size_t)b*U3STR + 2080 + c*8) = (u32x4){0,0,0,0};
    }
    // folded ct-table build (d-independent)
    if (blockIdx.y == 0 && blockIdx.x < 5) {
        int i = blockIdx.x*256 + tid;
        if (i < 1220) {
            int x0 = (i - 196) & 2047;
            int x1 = (i - 195) & 2047;
            float a0 = (float)(M_PI/(2.0*(double)LSEQ)) * (float)(2*x0 + 1);
            float a1 = (float)(M_PI/(2.0*(double)LSEQ)) * (float)(2*x1 + 1);
            float s0, c0, s1, c1;
            sincosf(a0, &s0, &c0);
            sincosf(a1, &s1, &c1);
            wct[i] = c0 / s0;
            wct[1232 + i] = c1 / s1;
        } else if (i < 1232) {
            wct[i] = 0.f; wct[1232 + i] = 0.f;
        }
    }
}

// ============================================================ fused kernel
#define MF(a, b, c) __builtin_amdgcn_mfma_f32_16x16x32_bf16((a), (b), (c), 0, 0, 0)

// one K-step: P = s mod 8. tile j uses ring slot (P-j)&7; prefetch next frag
// (tile0 of step s+1) into slot (P+1)&7 right after tile7 (its current owner)
// is consumed. B double-buffered on parity of s.
#define BODY(P) do {                                                        \
    const short8 bcur = Bb[(P) & 1];                                        \
    acc[7] = MF(A[((P)+1) & 7], bcur, acc[7]);                              \
    A[((P)+1) & 7] = *(const short8*)(sm + aAn);                            \
    Bb[((P)+1) & 1] = *(const short8*)(sm + aBn);                           \
    aAn += 64; aBn += 64;                                                   \
    acc[6] = MF(A[((P)+2) & 7], bcur, acc[6]);                              \
    acc[5] = MF(A[((P)+3) & 7], bcur, acc[5]);                              \
    acc[4] = MF(A[((P)+4) & 7], bcur, acc[4]);                              \
    acc[3] = MF(A[((P)+5) & 7], bcur, acc[3]);                              \
    acc[2] = MF(A[((P)+6) & 7], bcur, acc[2]);                              \
    acc[1] = MF(A[((P)+7) & 7], bcur, acc[1]);                              \
    acc[0] = MF(A[(P) & 7],     bcur, acc[0]);                              \
} while (0)

__global__ __launch_bounds__(512, 1) void s4d_fused4(
    const unsigned short* __restrict__ uimg, const float* __restrict__ wct,
    const float* __restrict__ A_real, const float* __restrict__ A_imag,
    const float* __restrict__ C_real, const float* __restrict__ C_imag,
    const float* __restrict__ Dvec, float* __restrict__ out)
{
    extern __shared__ __align__(16) unsigned char sm[];
    float* hRe  = (float*)(sm + OFF_HRE);
    float* hImE = (float*)(sm + OFF_HIE);
    float* hImO = (float*)(sm + OFF_HIO);

    const int tid = threadIdx.x;
    const int Bk  = blockIdx.x;
    const int d   = ((Bk & 7) << 5) | (Bk >> 3);   // XCD-swizzle

    // ---- issue global loads early
    const u32x4* gu = (const u32x4*)(uimg + (size_t)d*U3SH);
    u32x4 stg[5];
    #pragma unroll
    for (int r = 0; r < 5; ++r) {
        int i = tid + 512*r;
        if (i < U3SH/8) stg[r] = gu[i];
    }
    const f32x4* gct = (const f32x4*)wct;
    f32x4 ctg[2];
    ctg[0] = gct[tid];
    if (tid < 104) ctg[1] = gct[tid + 512];

    // ---- phase 0: power tables (lanes 0-31) + zero slot0 [0,1056)+[3104,4400)
    if (tid < 32) {
        const int n = tid;
        float ar = A_real[d*NHALF + n], ai = A_imag[d*NHALF + n];
        float cr = C_real[d*NHALF + n], ci = C_imag[d*NHALF + n];
        float amp = expf(-0.1f * expf(ar));
        float sn, cs; sincosf(0.1f * ai, &sn, &cs);
        float Adr = amp*cs, Adi = amp*sn;
        float* Pp = (float*)(sm + OFF_P);
        float* Qp = (float*)(sm + OFF_Q);
        float* Cp = (float*)(sm + OFF_C);
        float pr = 1.f, pi = 0.f;
        Pp[n*2] = pr; Pp[n*2 + 1] = pi;
        #pragma unroll
        for (int i = 1; i < 16; ++i) {
            float nr = pr*Adr - pi*Adi;
            float ni = pr*Adi + pi*Adr;
            pr = nr; pi = ni;
            Pp[i*68 + n*2] = pr; Pp[i*68 + n*2 + 1] = pi;
        }
        float a16r = pr*Adr - pi*Adi;
        float a16i = pr*Adi + pi*Adr;
        float qr = 1.f, qi = 0.f;
        Qp[n*2] = qr; Qp[n*2 + 1] = qi;
        #pragma unroll
        for (int j = 1; j < 24; ++j) {
            float nr = qr*a16r - qi*a16i;
            float ni = qr*a16i + qi*a16r;
            qr = nr; qi = ni;
            Qp[j*68 + n*2] = qr; Qp[j*68 + n*2 + 1] = qi;
        }
        Cp[n*2] = cr; Cp[n*2 + 1] = ci;
    }
    {
        int zi = tid - 64;                  // 294 zero-units
        if (zi >= 0 && zi < 294) {
            int off = (zi < 132) ? zi*16 : 6208 + (zi - 132)*16;
            *(u32x4*)(sm + OFF_K + off) = (u32x4){0,0,0,0};
        }
    }
    __syncthreads();

    // ---- phase B: write ct + u to LDS; h[tau] = sum_n C_n P[tau&15] Q[tau>>4]
    *(f32x4*)(sm + OFF_CT0 + tid*16) = ctg[0];
    if (tid < 104) *(f32x4*)(sm + OFF_CT0 + (tid + 512)*16) = ctg[1];
    #pragma unroll
    for (int r = 0; r < 5; ++r) {
        int i = tid + 512*r;
        if (i < U3SH/8) *(u32x4*)(sm + i*16) = stg[r];
    }
    if (tid < TM2) {
        const int tau = tid, ii = tau & 15, jj = tau >> 4;
        const float* Pr = (const float*)(sm + OFF_P) + ii*68;
        const float* Qr = (const float*)(sm + OFF_Q) + jj*68;
        const float* Cc = (const float*)(sm + OFF_C);
        float aR = 0.f, aI = 0.f;
        #pragma unroll 4
        for (int n = 0; n < 32; n += 2) {
            f32x4 p = *(const f32x4*)(Pr + 2*n);
            f32x4 q = *(const f32x4*)(Qr + 2*n);
            f32x4 c = *(const f32x4*)(Cc + 2*n);
            float w0r = p[0]*q[0] - p[1]*q[1];
            float w0i = p[0]*q[1] + p[1]*q[0];
            aR = fmaf(c[0], w0r, aR); aR = fmaf(-c[1], w0i, aR);
            aI = fmaf(c[0], w0i, aI); aI = fmaf( c[1], w0r, aI);
            float w1r = p[2]*q[2] - p[3]*q[3];
            float w1i = p[2]*q[3] + p[3]*q[2];
            aR = fmaf(c[2], w1r, aR); aR = fmaf(-c[3], w1i, aR);
            aI = fmaf(c[2], w1i, aI); aI = fmaf( c[3], w1r, aI);
        }
        hRe[tau] = aR;
        if (tau & 1) hImO[tau >> 1] = aI;
        else         hImE[tau >> 1] = aI;
    }
    __syncthreads();

    // ---- phase C: register-blocked Hilbert -> k into slot0 at shorts [1056+t]
    {
        const int pt = tid & 1;
        const int g  = tid >> 1;
        const float* tb = (const float*)(sm + (pt ? OFF_CT1 : OFF_CT0));
        const float* hb = (const float*)(sm + (pt ? OFF_HIE : OFF_HIO));

        float acc0 = 0.f, acc1 = 0.f, acc2 = 0.f, acc3 = 0.f;
        int qb = 4*g + 192;
        f32x4 Wlo = *(const f32x4*)(tb + qb);
        f32x4 Whi = *(const f32x4*)(tb + qb + 4);

        #pragma unroll 4
        for (int R = 0; R < 48; ++R) {
            f32x4 hv = *(const f32x4*)(hb + 4*R);
            f32x4 Wn = *(const f32x4*)(tb + qb - 4);
            acc0 = fmaf(Wlo[3], hv[0], acc0); acc1 = fmaf(Whi[0], hv[0], acc1);
            acc2 = fmaf(Whi[1], hv[0], acc2); acc3 = fmaf(Whi[2], hv[0], acc3);
            acc0 = fmaf(Wlo[2], hv[1], acc0); acc1 = fmaf(Wlo[3], hv[1], acc1);
            acc2 = fmaf(Whi[0], hv[1], acc2); acc3 = fmaf(Whi[1], hv[1], acc3);
            acc0 = fmaf(Wlo[1], hv[2], acc0); acc1 = fmaf(Wlo[2], hv[2], acc1);
            acc2 = fmaf(Wlo[3], hv[2], acc2); acc3 = fmaf(Whi[0], hv[2], acc3);
            acc0 = fmaf(Wlo[0], hv[3], acc0); acc1 = fmaf(Wlo[1], hv[3], acc1);
            acc2 = fmaf(Wlo[2], hv[3], acc2); acc3 = fmaf(Wlo[3], hv[3], acc3);
            Whi = Wlo; Wlo = Wn; qb -= 4;
        }

        unsigned short* slot0 = (unsigned short*)(sm + OFF_K);
        float accs[4] = {acc0, acc1, acc2, acc3};
        #pragma unroll
        for (int e = 0; e < 4; ++e) {
            int t = 8*g + 2*e + pt;
            float base = (t < TM2) ? hRe[t] : 0.f;
            float kv = base - accs[e] * (1.0f/(float)LSEQ);
            __hip_bfloat16 hbv = __float2bfloat16(kv);
            slot0[1056 + t] = *(unsigned short*)&hbv;
        }
    }
    __syncthreads();

    // ---- expand: S_c[zz] = S_0[zz + c] (forward shift), zz in [0, 4384)
    {
        const unsigned short* s0p = (const unsigned short*)(sm + OFF_K);
        for (int i = tid; i < 548; i += 512) {
            int z0 = i*8;
            u32x4 va = *(const u32x4*)(s0p + z0);
            u32x4 vb = *(const u32x4*)(s0p + z0 + 8);
            unsigned src[8] = { va[0], va[1], va[2], va[3],
                                vb[0], vb[1], vb[2], vb[3] };
            #pragma unroll
            for (int c = 1; c < 8; ++c) {
                u32x4 w;
                if ((c & 1) == 0) {
                    int q = c >> 1;
                    w = (u32x4){ src[q], src[q+1], src[q+2], src[q+3] };
                } else {
                    int q = (c - 1) >> 1;
                    w = (u32x4){ (src[q]   >> 16) | (src[q+1] << 16),
                                 (src[q+1] >> 16) | (src[q+2] << 16),
                                 (src[q+2] >> 16) | (src[q+3] << 16),
                                 (src[q+3] >> 16) | (src[q+4] << 16) };
                }
                *(u32x4*)(sm + OFF_K + c*KSLOT_STR + z0*2) = w;
            }
        }
    }
    __syncthreads();

    // ---- main loop: hi-packed Toeplitz MFMA.
    // taps: A[r=col][k=8h+e] = ker[m0 + 8h + e - t0w - 32j - col], m0 = 32s-32
    // B[k][(b,hi)] = u[b][m0 + 8h + e + 16*hi]
    const int lane = tid & 63, wv = tid >> 6;
    const int h    = lane >> 4;
    const int col  = lane & 15;
    const int t0w  = wv << 8;

    const int cA   = (7 - col) & 7;
    const int bA0  = OFF_K + cA*KSLOT_STR + 2*(2047 + 8*h - col - cA - t0w);
    const int laneB3 = (col & 7)*(U3STR*2) + 64 + 16*h + 32*(col >> 3);

    const float dv = Dvec[d];
    f32x4 acc[8];
    #pragma unroll
    for (int j = 0; j < 8; ++j) acc[j] = (f32x4){dv, dv, dv, dv};

    short8 A[8], Bb[2];
    #pragma unroll
    for (int w = 0; w < 8; ++w)            // slot w holds tile j=(8-w)&7 at s=0
        A[w] = *(const short8*)(sm + bA0 - 64*((8 - w) & 7));
    Bb[0] = *(const short8*)(sm + laneB3 - 64);

    int aAn = bA0 + 64;        // prefetch: tile0 frag of step s+1
    int aBn = laneB3;          // prefetch: B of step s+1

    BODY(0);                   // s = 0  (m0 = -32)
    for (int o = 0; o < 8; ++o) {          // s = 1..64
        BODY(1); BODY(2); BODY(3); BODY(4);
        BODY(5); BODY(6); BODY(7); BODY(0);
    }

    // ---- epilogue: C[r][(b,hi)] -> y[b][t0w + 32j + 16hi + 4h + reg]
    {
        const int b  = col & 7;
        const int hi16 = (col >> 3) << 4;
        float* ob = out + (size_t)b*LSEQ*DMODEL + d;
        #pragma unroll
        for (int j = 0; j < 8; ++j) {
            int trow = t0w + 32*j + hi16 + 4*h;
            float* o = ob + (size_t)trow*DMODEL;
            o[0*DMODEL] = acc[j][0];
            o[1*DMODEL] = acc[j][1];
            o[2*DMODEL] = acc[j][2];
            o[3*DMODEL] = acc[j][3];
        }
    }
}

// ============================================================ fallback (R1, verified)
__global__ __launch_bounds__(256) void s4d_build_k(
    const float* __restrict__ A_real, const float* __restrict__ A_imag,
    const float* __restrict__ C_real, const float* __restrict__ C_imag,
    float* __restrict__ kT)
{
    __shared__ float hRe[TMAX], hIm[TMAX], ct[LSEQ], prm[4][NHALF];
    const int tid = threadIdx.x;
    const int d   = blockIdx.x;
    if (tid < NHALF) {
        prm[0][tid] = A_real[d*NHALF + tid];
        prm[1][tid] = A_imag[d*NHALF + tid];
        prm[2][tid] = C_real[d*NHALF + tid];
        prm[3][tid] = C_imag[d*NHALF + tid];
    }
    #pragma unroll
    for (int r = 0; r < LSEQ/256; ++r) {
        int i = tid + 256*r;
        float ang = (float)(M_PI/(2.0*(double)LSEQ)) * (float)(2*i + 1);
        float sv, cv; sincosf(ang, &sv, &cv);
        ct[i] = cv / sv;
    }
    __syncthreads();
    for (int r = 0; r < TMAX/256; ++r) {
        int tau = tid + 256*r;
        float aR = 0.f, aI = 0.f;
        for (int n = 0; n < NHALF; ++n) {
            float lr  = -expf(prm[0][n]) * 0.1f;
            float amp = expf(lr * (float)tau);
            double ph = (double)prm[1][n] * 0.1 * (double)tau;
            ph -= floor(ph * (1.0/(2.0*M_PI))) * (2.0*M_PI);
            float sv, cv; sincosf((float)ph, &sv, &cv);
            float cr = prm[2][n], ci = prm[3][n];
            aR = fmaf(amp, cr*cv - ci*sv, aR);
            aI = fmaf(amp, cr*sv + ci*cv, aI);
        }
        hRe[tau] = aR; hIm[tau] = aI;
    }
    __syncthreads();
    float base[8], hsum[8];
    #pragma unroll
    for (int r = 0; r < 8; ++r) {
        base[r] = (r < 4) ? hRe[tid + 256*r] : 0.f;
        hsum[r] = 0.f;
    }
    const int tau0 = (tid & 1) ^ 1;
    for (int tau = tau0; tau < TMAX; tau += 2) {
        float him = hIm[tau];
        #pragma unroll
        for (int r = 0; r < 8; ++r) {
            int idx = ((tid + 256*r - tau) & (2*LSEQ - 1)) >> 1;
            hsum[r] = fmaf(ct[idx], him, hsum[r]);
        }
    }
    #pragma unroll
    for (int r = 0; r < 8; ++r) {
        int t = tid + 256*r;
        kT[(t + KPAD)*DMODEL + d] = base[r] - hsum[r] * (1.0f/(float)LSEQ);
    }
    if (tid < 2*KPAD) {
        int row = (tid < KPAD) ? tid : (LSEQ + KPAD + (tid - KPAD));
        kT[row*DMODEL + d] = 0.f;
    }
}

__global__ __launch_bounds__(256) void s4d_conv(
    const float* __restrict__ u, const float* __restrict__ Dvec,
    const float* __restrict__ kT, float* __restrict__ out)
{
    const int d  = threadIdx.x;
    const int t0 = blockIdx.x * TT;
    const int b  = blockIdx.y;
    float dvv = Dvec[d];
    float acc[TT];
    #pragma unroll
    for (int i = 0; i < TT; ++i) acc[i] = dvv;
    const float* ub   = u + (size_t)b * LSEQ * DMODEL + d;
    const float* kcol = kT + d;
    int mstart = t0 - 1024; if (mstart < 0) mstart = 0;
    int mend   = t0 + 1040; if (mend > LSEQ) mend = LSEQ;
    float kreg[31];
    {
        int jpb = mstart - t0 + 1024;
        #pragma unroll
        for (int r = 0; r < 31; ++r) kreg[r] = kcol[(jpb + r)*DMODEL];
    }
    for (int m0 = mstart; m0 < mend; m0 += TT) {
        float ureg[TT];
        #pragma unroll
        for (int mm = 0; mm < TT; ++mm) ureg[mm] = ub[(m0 + mm)*DMODEL];
        float knew[TT];
        if (m0 + TT < mend) {
            int jnb = m0 - t0 + 1024 + 31;
            #pragma unroll
            for (int r = 0; r < TT; ++r) knew[r] = kcol[(jnb + r)*DMODEL];
        } else {
            #pragma unroll
            for (int r = 0; r < TT; ++r) knew[r] = 0.f;
        }
        #pragma unroll
        for (int mm = 0; mm < TT; ++mm)
            #pragma unroll
            for (int tt = 0; tt < TT; ++tt)
                acc[tt] = fmaf(ureg[mm], kreg[mm - tt + 15], acc[tt]);
        #pragma unroll
        for (int r = 0; r < 15; ++r) kreg[r] = kreg[r + 16];
        #pragma unroll
        for (int r = 0; r < 16; ++r) kreg[15 + r] = knew[r];
    }
    float* ob = out + ((size_t)b * LSEQ + t0) * DMODEL + d;
    #pragma unroll
    for (int tt = 0; tt < TT; ++tt) ob[tt*DMODEL] = acc[tt];
}

// ============================================================ launch
extern "C" void kernel_launch(void* const* d_in, const int* in_sizes, int n_in,
                              void* d_out, int out_size, void* d_ws, size_t ws_size,
                              hipStream_t stream)
{
    const float* u  = (const float*)d_in[0];
    const float* Ar = (const float*)d_in[1];
    const float* Ai = (const float*)d_in[2];
    const float* Cr = (const float*)d_in[3];
    const float* Ci = (const float*)d_in[4];
    const float* Dv = (const float*)d_in[5];
    float* out = (float*)d_out;
    int B = in_sizes[0] / (LSEQ * DMODEL);

    if (B == 8 && ws_size >= WS_NEED2) {
        unsigned short* uimg = (unsigned short*)d_ws;
        float* wct = (float*)((unsigned char*)d_ws + WS_CT_OFF);
        hipFuncSetAttribute((const void*)s4d_fused4,
                            hipFuncAttributeMaxDynamicSharedMemorySize, SMEM_F3);
        s4d_utr<<<dim3(LSEQ/64, 8), 256, 0, stream>>>(u, uimg, wct);
        s4d_fused4<<<DMODEL, 512, SMEM_F3, stream>>>(uimg, wct, Ar, Ai, Cr, Ci, Dv, out);
    } else {
        float* kT = (float*)d_ws;
        s4d_build_k<<<DMODEL, 256, 0, stream>>>(Ar, Ai, Cr, Ci, kT);
        s4d_conv<<<dim3(LSEQ/TT, B), 256, 0, stream>>>(u, Dv, kT, out);
    }
}

// Round 10
// 40.268 us; speedup vs baseline: 1.5943x; 1.1697x over previous
//
#include <hip/hip_runtime.h>
#include <hip/hip_bf16.h>
#include <math.h>

#define LSEQ   2048
#define DMODEL 256
#define NHALF  32
#define TMAX   1024                 // fallback-path truncation
#define TM2    384                  // fast-path truncation
#define KPAD   16
#define KROWS  (LSEQ + 2*KPAD)
#define TT     16

typedef __attribute__((ext_vector_type(8))) short short8;
typedef __attribute__((ext_vector_type(4))) float f32x4;
typedef __attribute__((ext_vector_type(4))) unsigned int u32x4;

// ---- hi-packed MFMA geometry (R9-verified) ------------------------------
#define U3STR   2120                      // u row: 32 zero lead + 2048 + 40 zero tail
#define U3SH    (8*U3STR)                 // 16960 shorts per d
#define U3BYTES (U3SH*2)                  // 33920
#define KSLOT_STR 8848                    // k-copy stride in LDS (16 mod 128)
#define OFF_K    U3BYTES                  // slot c at OFF_K + c*KSLOT_STR
#define SMEM_F3  (OFF_K + 8*KSLOT_STR)    // 104704 dyn LDS for mfma kernel
#define KBF_SH   4400                     // shorts per d of the slot0 image in ws
// ---- ws layout
#define UIMG_SHORTS ((size_t)DMODEL*U3SH)
#define KBF_OFF_SH  UIMG_SHORTS
#define YT_OFF_B    ((UIMG_SHORTS + (size_t)DMODEL*KBF_SH)*2)
#define WS_NEED3    (YT_OFF_B + (size_t)8*LSEQ*DMODEL*4)

// ---- prep kernel shared-buffer overlay (bytes)
#define PB_CT0 0
#define PB_CT1 4928
#define PB_HRE 9856
#define PB_HIE 11392
#define PB_HIO 12160
#define PB_P   12928
#define PB_Q   17280
#define PB_C   23808
#define PB_BYTES 33792                    // = tr[256][66] shorts (transpose branch)

// ============================================================ prep kernel:
// grid (32, 16), 512 threads.
//   blockIdx.y <  8 : transpose u [B][L][D] f32 -> uimg [d][b][32+m] bf16
//   blockIdx.y >= 8 : build k for d=(y-8)*32+x -> kbf[d][0..4400) (zeros incl.)
__global__ __launch_bounds__(512, 2) void s4d_prep(
    const float* __restrict__ u,
    const float* __restrict__ A_real, const float* __restrict__ A_imag,
    const float* __restrict__ C_real, const float* __restrict__ C_imag,
    unsigned short* __restrict__ uimg, unsigned short* __restrict__ kbf)
{
    __shared__ __align__(16) unsigned char pbuf[PB_BYTES];
    const int tid = threadIdx.x;

    if (blockIdx.y < 8) {
        // ---------- transpose branch (R9 utr widened to 512 thr, R5 pattern)
        unsigned short (*tr)[66] = (unsigned short (*)[66])pbuf;
        const int m0 = blockIdx.x * 64;
        const int b  = blockIdx.y;

        const int mmBase = tid >> 6;          // 0..7
        const int d4     = (tid & 63) * 4;
        #pragma unroll
        for (int it = 0; it < 8; ++it) {
            int mm = it*8 + mmBase;
            const float* src = u + ((size_t)b*LSEQ + m0 + mm)*DMODEL + d4;
            f32x4 v = *(const f32x4*)src;
            #pragma unroll
            for (int j = 0; j < 4; ++j) {
                __hip_bfloat16 hb = __float2bfloat16(v[j]);
                tr[d4+j][mm] = *(unsigned short*)&hb;
            }
        }
        __syncthreads();
        #pragma unroll
        for (int P = 0; P < 4; ++P) {
            int d = P*64 + (tid >> 3);
            int c = tid & 7;
            const unsigned short* s = &tr[d][c*8];
            u32x4 w = { *(const unsigned*)(s),   *(const unsigned*)(s+2),
                        *(const unsigned*)(s+4), *(const unsigned*)(s+6) };
            *(u32x4*)(uimg + (size_t)d*U3SH + (size_t)b*U3STR + 32 + m0 + c*8) = w;
        }
        // zero pads: lead 32 shorts (x==0), tail 40 shorts (x==31)
        if (blockIdx.x == 0 && tid < 256) {
            int d = tid;
            #pragma unroll
            for (int c = 0; c < 4; ++c)
                *(u32x4*)(uimg + (size_t)d*U3SH + (size_t)b*U3STR + c*8) = (u32x4){0,0,0,0};
        } else if (blockIdx.x == 31 && tid < 256) {
            int d = tid;
            #pragma unroll
            for (int c = 0; c < 5; ++c)
                *(u32x4*)(uimg + (size_t)d*U3SH + (size_t)b*U3STR + 2080 + c*8) = (u32x4){0,0,0,0};
        }
    } else {
        // ---------- build branch (fused4 phases 0/B/C, verified math)
        const int d = (blockIdx.y - 8)*32 + blockIdx.x;
        float* ctL0 = (float*)(pbuf + PB_CT0);
        float* ctL1 = (float*)(pbuf + PB_CT1);
        float* hRe  = (float*)(pbuf + PB_HRE);
        float* hImE = (float*)(pbuf + PB_HIE);
        float* hImO = (float*)(pbuf + PB_HIO);
        float* Pp   = (float*)(pbuf + PB_P);
        float* Qp   = (float*)(pbuf + PB_Q);
        float* Cp   = (float*)(pbuf + PB_C);

        for (int i = tid; i < 1220; i += 512) {
            int x0 = (i - 196) & 2047;
            int x1 = (i - 195) & 2047;
            float a0 = (float)(M_PI/(2.0*(double)LSEQ)) * (float)(2*x0 + 1);
            float a1 = (float)(M_PI/(2.0*(double)LSEQ)) * (float)(2*x1 + 1);
            float s0, c0, s1, c1;
            sincosf(a0, &s0, &c0);
            sincosf(a1, &s1, &c1);
            ctL0[i] = c0 / s0;
            ctL1[i] = c1 / s1;
        }
        if (tid < 32) {
            const int n = tid;
            float ar = A_real[d*NHALF + n], ai = A_imag[d*NHALF + n];
            float cr = C_real[d*NHALF + n], ci = C_imag[d*NHALF + n];
            float amp = expf(-0.1f * expf(ar));
            float sn, cs; sincosf(0.1f * ai, &sn, &cs);
            float Adr = amp*cs, Adi = amp*sn;
            float pr = 1.f, pi = 0.f;
            Pp[n*2] = pr; Pp[n*2 + 1] = pi;
            #pragma unroll
            for (int i = 1; i < 16; ++i) {
                float nr = pr*Adr - pi*Adi;
                float ni = pr*Adi + pi*Adr;
                pr = nr; pi = ni;
                Pp[i*68 + n*2] = pr; Pp[i*68 + n*2 + 1] = pi;
            }
            float a16r = pr*Adr - pi*Adi;
            float a16i = pr*Adi + pi*Adr;
            float qr = 1.f, qi = 0.f;
            Qp[n*2] = qr; Qp[n*2 + 1] = qi;
            #pragma unroll
            for (int j = 1; j < 24; ++j) {
                float nr = qr*a16r - qi*a16i;
                float ni = qr*a16i + qi*a16r;
                qr = nr; qi = ni;
                Qp[j*68 + n*2] = qr; Qp[j*68 + n*2 + 1] = qi;
            }
            Cp[n*2] = cr; Cp[n*2 + 1] = ci;
        }
        __syncthreads();

        if (tid < TM2) {
            const int tau = tid, ii = tau & 15, jj = tau >> 4;
            const float* Pr = Pp + ii*68;
            const float* Qr = Qp + jj*68;
            float aR = 0.f, aI = 0.f;
            #pragma unroll 4
            for (int n = 0; n < 32; n += 2) {
                f32x4 p = *(const f32x4*)(Pr + 2*n);
                f32x4 q = *(const f32x4*)(Qr + 2*n);
                f32x4 c = *(const f32x4*)(Cp + 2*n);
                float w0r = p[0]*q[0] - p[1]*q[1];
                float w0i = p[0]*q[1] + p[1]*q[0];
                aR = fmaf(c[0], w0r, aR); aR = fmaf(-c[1], w0i, aR);
                aI = fmaf(c[0], w0i, aI); aI = fmaf( c[1], w0r, aI);
                float w1r = p[2]*q[2] - p[3]*q[3];
                float w1i = p[2]*q[3] + p[3]*q[2];
                aR = fmaf(c[2], w1r, aR); aR = fmaf(-c[3], w1i, aR);
                aI = fmaf(c[2], w1i, aI); aI = fmaf( c[3], w1r, aI);
            }
            hRe[tau] = aR;
            if (tau & 1) hImO[tau >> 1] = aI;
            else         hImE[tau >> 1] = aI;
        }
        __syncthreads();

        unsigned short* kd = kbf + (size_t)d*KBF_SH;
        {
            const int pt = tid & 1;
            const int g  = tid >> 1;
            const float* tb = pt ? ctL1 : ctL0;
            const float* hb = pt ? hImE : hImO;

            float acc0 = 0.f, acc1 = 0.f, acc2 = 0.f, acc3 = 0.f;
            int qb = 4*g + 192;
            f32x4 Wlo = *(const f32x4*)(tb + qb);
            f32x4 Whi = *(const f32x4*)(tb + qb + 4);

            #pragma unroll 4
            for (int R = 0; R < 48; ++R) {
                f32x4 hv = *(const f32x4*)(hb + 4*R);
                f32x4 Wn = *(const f32x4*)(tb + qb - 4);
                acc0 = fmaf(Wlo[3], hv[0], acc0); acc1 = fmaf(Whi[0], hv[0], acc1);
                acc2 = fmaf(Whi[1], hv[0], acc2); acc3 = fmaf(Whi[2], hv[0], acc3);
                acc0 = fmaf(Wlo[2], hv[1], acc0); acc1 = fmaf(Wlo[3], hv[1], acc1);
                acc2 = fmaf(Whi[0], hv[1], acc2); acc3 = fmaf(Whi[1], hv[1], acc3);
                acc0 = fmaf(Wlo[1], hv[2], acc0); acc1 = fmaf(Wlo[2], hv[2], acc1);
                acc2 = fmaf(Wlo[3], hv[2], acc2); acc3 = fmaf(Whi[0], hv[2], acc3);
                acc0 = fmaf(Wlo[0], hv[3], acc0); acc1 = fmaf(Wlo[1], hv[3], acc1);
                acc2 = fmaf(Wlo[2], hv[3], acc2); acc3 = fmaf(Wlo[3], hv[3], acc3);
                Whi = Wlo; Wlo = Wn; qb -= 4;
            }

            float accs[4] = {acc0, acc1, acc2, acc3};
            #pragma unroll
            for (int e = 0; e < 4; ++e) {
                int t = 8*g + 2*e + pt;
                float base = (t < TM2) ? hRe[t] : 0.f;
                float kv = base - accs[e] * (1.0f/(float)LSEQ);
                __hip_bfloat16 hbv = __float2bfloat16(kv);
                kd[1056 + t] = *(unsigned short*)&hbv;
            }
        }
        // zero head [0,1056) shorts = 132 u32x4; tail [3104,4400) = 162 u32x4
        if (tid < 132) *(u32x4*)((unsigned char*)kd + tid*16) = (u32x4){0,0,0,0};
        if (tid < 162) *(u32x4*)((unsigned char*)kd + 6208 + tid*16) = (u32x4){0,0,0,0};
    }
}

// ============================================================ mfma kernel
#define MF(a, b, c) __builtin_amdgcn_mfma_f32_16x16x32_bf16((a), (b), (c), 0, 0, 0)

#define BODY(P) do {                                                        \
    const short8 bcur = Bb[(P) & 1];                                        \
    acc[7] = MF(A[((P)+1) & 7], bcur, acc[7]);                              \
    A[((P)+1) & 7] = *(const short8*)(sm + aAn);                            \
    Bb[((P)+1) & 1] = *(const short8*)(sm + aBn);                           \
    aAn += 64; aBn += 64;                                                   \
    acc[6] = MF(A[((P)+2) & 7], bcur, acc[6]);                              \
    acc[5] = MF(A[((P)+3) & 7], bcur, acc[5]);                              \
    acc[4] = MF(A[((P)+4) & 7], bcur, acc[4]);                              \
    acc[3] = MF(A[((P)+5) & 7], bcur, acc[3]);                              \
    acc[2] = MF(A[((P)+6) & 7], bcur, acc[2]);                              \
    acc[1] = MF(A[((P)+7) & 7], bcur, acc[1]);                              \
    acc[0] = MF(A[(P) & 7],     bcur, acc[0]);                              \
} while (0)

__global__ __launch_bounds__(512, 1) void s4d_mfma9(
    const unsigned short* __restrict__ uimg, const unsigned short* __restrict__ kbf,
    const float* __restrict__ Dvec, float* __restrict__ yT)
{
    extern __shared__ __align__(16) unsigned char sm[];
    const int tid = threadIdx.x;
    const int Bk  = blockIdx.x;
    const int d   = ((Bk & 7) << 5) | (Bk >> 3);   // XCD-swizzle

    // ---- stage u (2120 u32x4) + kbf (550 u32x4) via regs
    const u32x4* gu = (const u32x4*)(uimg + (size_t)d*U3SH);
    const u32x4* gk = (const u32x4*)(kbf + (size_t)d*KBF_SH);
    u32x4 stg[5], kst[2];
    #pragma unroll
    for (int r = 0; r < 5; ++r) {
        int i = tid + 512*r;
        if (i < U3SH/8) stg[r] = gu[i];
    }
    #pragma unroll
    for (int r = 0; r < 2; ++r) {
        int i = tid + 512*r;
        if (i < KBF_SH/8) kst[r] = gk[i];
    }
    #pragma unroll
    for (int r = 0; r < 5; ++r) {
        int i = tid + 512*r;
        if (i < U3SH/8) *(u32x4*)(sm + i*16) = stg[r];
    }
    #pragma unroll
    for (int r = 0; r < 2; ++r) {
        int i = tid + 512*r;
        if (i < KBF_SH/8) *(u32x4*)(sm + OFF_K + i*16) = kst[r];
    }
    __syncthreads();

    // ---- expand: slots 1..7 from slot0 (verified R9)
    {
        const unsigned short* s0p = (const unsigned short*)(sm + OFF_K);
        for (int i = tid; i < 548; i += 512) {
            int z0 = i*8;
            u32x4 va = *(const u32x4*)(s0p + z0);
            u32x4 vb = *(const u32x4*)(s0p + z0 + 8);
            unsigned src[8] = { va[0], va[1], va[2], va[3],
                                vb[0], vb[1], vb[2], vb[3] };
            #pragma unroll
            for (int c = 1; c < 8; ++c) {
                u32x4 w;
                if ((c & 1) == 0) {
                    int q = c >> 1;
                    w = (u32x4){ src[q], src[q+1], src[q+2], src[q+3] };
                } else {
                    int q = (c - 1) >> 1;
                    w = (u32x4){ (src[q]   >> 16) | (src[q+1] << 16),
                                 (src[q+1] >> 16) | (src[q+2] << 16),
                                 (src[q+2] >> 16) | (src[q+3] << 16),
                                 (src[q+3] >> 16) | (src[q+4] << 16) };
                }
                *(u32x4*)(sm + OFF_K + c*KSLOT_STR + z0*2) = w;
            }
        }
    }
    __syncthreads();

    // ---- main loop (byte-identical to verified R9)
    const int lane = tid & 63, wv = tid >> 6;
    const int h    = lane >> 4;
    const int col  = lane & 15;
    const int t0w  = wv << 8;

    const int cA   = (7 - col) & 7;
    const int bA0  = OFF_K + cA*KSLOT_STR + 2*(2047 + 8*h - col - cA - t0w);
    const int laneB3 = (col & 7)*(U3STR*2) + 64 + 16*h + 32*(col >> 3);

    const float dv = Dvec[d];
    f32x4 acc[8];
    #pragma unroll
    for (int j = 0; j < 8; ++j) acc[j] = (f32x4){dv, dv, dv, dv};

    short8 A[8], Bb[2];
    #pragma unroll
    for (int w = 0; w < 8; ++w)
        A[w] = *(const short8*)(sm + bA0 - 64*((8 - w) & 7));
    Bb[0] = *(const short8*)(sm + laneB3 - 64);

    int aAn = bA0 + 64;
    int aBn = laneB3;

    BODY(0);
    for (int o = 0; o < 8; ++o) {
        BODY(1); BODY(2); BODY(3); BODY(4);
        BODY(5); BODY(6); BODY(7); BODY(0);
    }

    // ---- epilogue: f32x4 to yT[d][b][t] (t contiguous per lane)
    {
        const int b    = col & 7;
        const int hi16 = (col >> 3) << 4;
        float* yb = yT + (size_t)d*(8*LSEQ) + (size_t)b*LSEQ;
        #pragma unroll
        for (int j = 0; j < 8; ++j) {
            int trow = t0w + 32*j + hi16 + 4*h;
            *(f32x4*)(yb + trow) = acc[j];
        }
    }
}

// ============================================================ yT -> out transpose
// block (t-tile 32, b), 256 threads; coalesced read (256B/d) + write (1KB rows)
__global__ __launch_bounds__(256) void s4d_ytr(const float* __restrict__ yT,
                                               float* __restrict__ out)
{
    __shared__ float tr2[32][260];
    const int tid = threadIdx.x;
    const int t0  = blockIdx.x * 32;
    const int b   = blockIdx.y;

    {
        const int dd = tid;
        const float* src = yT + (size_t)dd*(8*LSEQ) + (size_t)b*LSEQ + t0;
        #pragma unroll
        for (int c = 0; c < 8; ++c) {
            f32x4 v = *(const f32x4*)(src + c*4);
            #pragma unroll
            for (int e = 0; e < 4; ++e) tr2[c*4 + e][dd] = v[e];
        }
    }
    __syncthreads();
    {
        const int d4  = (tid & 63) * 4;
        const int ttB = tid >> 6;
        #pragma unroll
        for (int s = 0; s < 8; ++s) {
            int tt = s*4 + ttB;
            f32x4 w = { tr2[tt][d4], tr2[tt][d4+1], tr2[tt][d4+2], tr2[tt][d4+3] };
            *(f32x4*)(out + ((size_t)b*LSEQ + t0 + tt)*DMODEL + d4) = w;
        }
    }
}

// ============================================================ fallback (R1, verified)
__global__ __launch_bounds__(256) void s4d_build_k(
    const float* __restrict__ A_real, const float* __restrict__ A_imag,
    const float* __restrict__ C_real, const float* __restrict__ C_imag,
    float* __restrict__ kT)
{
    __shared__ float hRe[TMAX], hIm[TMAX], ct[LSEQ], prm[4][NHALF];
    const int tid = threadIdx.x;
    const int d   = blockIdx.x;
    if (tid < NHALF) {
        prm[0][tid] = A_real[d*NHALF + tid];
        prm[1][tid] = A_imag[d*NHALF + tid];
        prm[2][tid] = C_real[d*NHALF + tid];
        prm[3][tid] = C_imag[d*NHALF + tid];
    }
    #pragma unroll
    for (int r = 0; r < LSEQ/256; ++r) {
        int i = tid + 256*r;
        float ang = (float)(M_PI/(2.0*(double)LSEQ)) * (float)(2*i + 1);
        float sv, cv; sincosf(ang, &sv, &cv);
        ct[i] = cv / sv;
    }
    __syncthreads();
    for (int r = 0; r < TMAX/256; ++r) {
        int tau = tid + 256*r;
        float aR = 0.f, aI = 0.f;
        for (int n = 0; n < NHALF; ++n) {
            float lr  = -expf(prm[0][n]) * 0.1f;
            float amp = expf(lr * (float)tau);
            double ph = (double)prm[1][n] * 0.1 * (double)tau;
            ph -= floor(ph * (1.0/(2.0*M_PI))) * (2.0*M_PI);
            float sv, cv; sincosf((float)ph, &sv, &cv);
            float cr = prm[2][n], ci = prm[3][n];
            aR = fmaf(amp, cr*cv - ci*sv, aR);
            aI = fmaf(amp, cr*sv + ci*cv, aI);
        }
        hRe[tau] = aR; hIm[tau] = aI;
    }
    __syncthreads();
    float base[8], hsum[8];
    #pragma unroll
    for (int r = 0; r < 8; ++r) {
        base[r] = (r < 4) ? hRe[tid + 256*r] : 0.f;
        hsum[r] = 0.f;
    }
    const int tau0 = (tid & 1) ^ 1;
    for (int tau = tau0; tau < TMAX; tau += 2) {
        float him = hIm[tau];
        #pragma unroll
        for (int r = 0; r < 8; ++r) {
            int idx = ((tid + 256*r - tau) & (2*LSEQ - 1)) >> 1;
            hsum[r] = fmaf(ct[idx], him, hsum[r]);
        }
    }
    #pragma unroll
    for (int r = 0; r < 8; ++r) {
        int t = tid + 256*r;
        kT[(t + KPAD)*DMODEL + d] = base[r] - hsum[r] * (1.0f/(float)LSEQ);
    }
    if (tid < 2*KPAD) {
        int row = (tid < KPAD) ? tid : (LSEQ + KPAD + (tid - KPAD));
        kT[row*DMODEL + d] = 0.f;
    }
}

__global__ __launch_bounds__(256) void s4d_conv(
    const float* __restrict__ u, const float* __restrict__ Dvec,
    const float* __restrict__ kT, float* __restrict__ out)
{
    const int d  = threadIdx.x;
    const int t0 = blockIdx.x * TT;
    const int b  = blockIdx.y;
    float dvv = Dvec[d];
    float acc[TT];
    #pragma unroll
    for (int i = 0; i < TT; ++i) acc[i] = dvv;
    const float* ub   = u + (size_t)b * LSEQ * DMODEL + d;
    const float* kcol = kT + d;
    int mstart = t0 - 1024; if (mstart < 0) mstart = 0;
    int mend   = t0 + 1040; if (mend > LSEQ) mend = LSEQ;
    float kreg[31];
    {
        int jpb = mstart - t0 + 1024;
        #pragma unroll
        for (int r = 0; r < 31; ++r) kreg[r] = kcol[(jpb + r)*DMODEL];
    }
    for (int m0 = mstart; m0 < mend; m0 += TT) {
        float ureg[TT];
        #pragma unroll
        for (int mm = 0; mm < TT; ++mm) ureg[mm] = ub[(m0 + mm)*DMODEL];
        float knew[TT];
        if (m0 + TT < mend) {
            int jnb = m0 - t0 + 1024 + 31;
            #pragma unroll
            for (int r = 0; r < TT; ++r) knew[r] = kcol[(jnb + r)*DMODEL];
        } else {
            #pragma unroll
            for (int r = 0; r < TT; ++r) knew[r] = 0.f;
        }
        #pragma unroll
        for (int mm = 0; mm < TT; ++mm)
            #pragma unroll
            for (int tt = 0; tt < TT; ++tt)
                acc[tt] = fmaf(ureg[mm], kreg[mm - tt + 15], acc[tt]);
        #pragma unroll
        for (int r = 0; r < 15; ++r) kreg[r] = kreg[r + 16];
        #pragma unroll
        for (int r = 0; r < 16; ++r) kreg[15 + r] = knew[r];
    }
    float* ob = out + ((size_t)b * LSEQ + t0) * DMODEL + d;
    #pragma unroll
    for (int tt = 0; tt < TT; ++tt) ob[tt*DMODEL] = acc[tt];
}

// ============================================================ launch
extern "C" void kernel_launch(void* const* d_in, const int* in_sizes, int n_in,
                              void* d_out, int out_size, void* d_ws, size_t ws_size,
                              hipStream_t stream)
{
    const float* u  = (const float*)d_in[0];
    const float* Ar = (const float*)d_in[1];
    const float* Ai = (const float*)d_in[2];
    const float* Cr = (const float*)d_in[3];
    const float* Ci = (const float*)d_in[4];
    const float* Dv = (const float*)d_in[5];
    float* out = (float*)d_out;
    int B = in_sizes[0] / (LSEQ * DMODEL);

    if (B == 8 && ws_size >= WS_NEED3) {
        unsigned short* uimg = (unsigned short*)d_ws;
        unsigned short* kbf  = uimg + KBF_OFF_SH;
        float* yT = (float*)((unsigned char*)d_ws + YT_OFF_B);
        hipFuncSetAttribute((const void*)s4d_mfma9,
                            hipFuncAttributeMaxDynamicSharedMemorySize, SMEM_F3);
        s4d_prep<<<dim3(32, 16), 512, 0, stream>>>(u, Ar, Ai, Cr, Ci, uimg, kbf);
        s4d_mfma9<<<DMODEL, 512, SMEM_F3, stream>>>(uimg, kbf, Dv, yT);
        s4d_ytr<<<dim3(LSEQ/32, 8), 256, 0, stream>>>(yT, out);
    } else {
        float* kT = (float*)d_ws;
        s4d_build_k<<<DMODEL, 256, 0, stream>>>(Ar, Ai, Cr, Ci, kT);
        s4d_conv<<<dim3(LSEQ/TT, B), 256, 0, stream>>>(u, Dv, kT, out);
    }
}

// Round 11
// 40.027 us; speedup vs baseline: 1.6039x; 1.0060x over previous
//
#include <hip/hip_runtime.h>
#include <hip/hip_bf16.h>
#include <math.h>

#define LSEQ   2048
#define DMODEL 256
#define NHALF  32
#define TMAX   1024                 // fallback-path truncation
#define TM2    384                  // fast-path truncation
#define KPAD   16
#define KROWS  (LSEQ + 2*KPAD)
#define TT     16

typedef __attribute__((ext_vector_type(8))) short short8;
typedef __attribute__((ext_vector_type(4))) float f32x4;
typedef __attribute__((ext_vector_type(4))) unsigned int u32x4;

// ---- hi-packed MFMA geometry (R9/R10-verified) ---------------------------
#define U3STR   2120                      // u row: 32 zero lead + 2048 + 40 zero tail
#define U3SH    (8*U3STR)                 // 16960 shorts per d
#define U3BYTES (U3SH*2)                  // 33920
#define KSLOT_STR 8848                    // k-copy stride in LDS (16 mod 128)
#define OFF_K    U3BYTES                  // slot c at OFF_K + c*KSLOT_STR
#define SMEM_F3  (OFF_K + 8*KSLOT_STR)    // 104704 dyn LDS for mfma kernel
#define KBF_SH   4400                     // shorts per d of the slot0 image in ws
#define YTR_SMEM (64*260*4)               // 66560 dyn LDS for ytr
// ---- ws layout
#define UIMG_SHORTS ((size_t)DMODEL*U3SH)
#define KBF_OFF_SH  UIMG_SHORTS
#define YT_OFF_B    ((UIMG_SHORTS + (size_t)DMODEL*KBF_SH)*2)
#define WS_NEED3    (YT_OFF_B + (size_t)8*LSEQ*DMODEL*4)

// ---- prep kernel shared-buffer overlay (bytes)
#define PB_CT0 0
#define PB_CT1 4928
#define PB_HRE 9856
#define PB_HIE 11392
#define PB_HIO 12160
#define PB_P   12928
#define PB_Q   17280
#define PB_C   23808
#define PB_BYTES 33792

// ============================================================ prep kernel (R10-verified):
__global__ __launch_bounds__(512, 2) void s4d_prep(
    const float* __restrict__ u,
    const float* __restrict__ A_real, const float* __restrict__ A_imag,
    const float* __restrict__ C_real, const float* __restrict__ C_imag,
    unsigned short* __restrict__ uimg, unsigned short* __restrict__ kbf)
{
    __shared__ __align__(16) unsigned char pbuf[PB_BYTES];
    const int tid = threadIdx.x;

    if (blockIdx.y < 8) {
        unsigned short (*tr)[66] = (unsigned short (*)[66])pbuf;
        const int m0 = blockIdx.x * 64;
        const int b  = blockIdx.y;

        const int mmBase = tid >> 6;
        const int d4     = (tid & 63) * 4;
        #pragma unroll
        for (int it = 0; it < 8; ++it) {
            int mm = it*8 + mmBase;
            const float* src = u + ((size_t)b*LSEQ + m0 + mm)*DMODEL + d4;
            f32x4 v = *(const f32x4*)src;
            #pragma unroll
            for (int j = 0; j < 4; ++j) {
                __hip_bfloat16 hb = __float2bfloat16(v[j]);
                tr[d4+j][mm] = *(unsigned short*)&hb;
            }
        }
        __syncthreads();
        #pragma unroll
        for (int P = 0; P < 4; ++P) {
            int d = P*64 + (tid >> 3);
            int c = tid & 7;
            const unsigned short* s = &tr[d][c*8];
            u32x4 w = { *(const unsigned*)(s),   *(const unsigned*)(s+2),
                        *(const unsigned*)(s+4), *(const unsigned*)(s+6) };
            *(u32x4*)(uimg + (size_t)d*U3SH + (size_t)b*U3STR + 32 + m0 + c*8) = w;
        }
        if (blockIdx.x == 0 && tid < 256) {
            int d = tid;
            #pragma unroll
            for (int c = 0; c < 4; ++c)
                *(u32x4*)(uimg + (size_t)d*U3SH + (size_t)b*U3STR + c*8) = (u32x4){0,0,0,0};
        } else if (blockIdx.x == 31 && tid < 256) {
            int d = tid;
            #pragma unroll
            for (int c = 0; c < 5; ++c)
                *(u32x4*)(uimg + (size_t)d*U3SH + (size_t)b*U3STR + 2080 + c*8) = (u32x4){0,0,0,0};
        }
    } else {
        const int d = (blockIdx.y - 8)*32 + blockIdx.x;
        float* ctL0 = (float*)(pbuf + PB_CT0);
        float* ctL1 = (float*)(pbuf + PB_CT1);
        float* hRe  = (float*)(pbuf + PB_HRE);
        float* hImE = (float*)(pbuf + PB_HIE);
        float* hImO = (float*)(pbuf + PB_HIO);
        float* Pp   = (float*)(pbuf + PB_P);
        float* Qp   = (float*)(pbuf + PB_Q);
        float* Cp   = (float*)(pbuf + PB_C);

        for (int i = tid; i < 1220; i += 512) {
            int x0 = (i - 196) & 2047;
            int x1 = (i - 195) & 2047;
            float a0 = (float)(M_PI/(2.0*(double)LSEQ)) * (float)(2*x0 + 1);
            float a1 = (float)(M_PI/(2.0*(double)LSEQ)) * (float)(2*x1 + 1);
            float s0, c0, s1, c1;
            sincosf(a0, &s0, &c0);
            sincosf(a1, &s1, &c1);
            ctL0[i] = c0 / s0;
            ctL1[i] = c1 / s1;
        }
        if (tid < 32) {
            const int n = tid;
            float ar = A_real[d*NHALF + n], ai = A_imag[d*NHALF + n];
            float cr = C_real[d*NHALF + n], ci = C_imag[d*NHALF + n];
            float amp = expf(-0.1f * expf(ar));
            float sn, cs; sincosf(0.1f * ai, &sn, &cs);
            float Adr = amp*cs, Adi = amp*sn;
            float pr = 1.f, pi = 0.f;
            Pp[n*2] = pr; Pp[n*2 + 1] = pi;
            #pragma unroll
            for (int i = 1; i < 16; ++i) {
                float nr = pr*Adr - pi*Adi;
                float ni = pr*Adi + pi*Adr;
                pr = nr; pi = ni;
                Pp[i*68 + n*2] = pr; Pp[i*68 + n*2 + 1] = pi;
            }
            float a16r = pr*Adr - pi*Adi;
            float a16i = pr*Adi + pi*Adr;
            float qr = 1.f, qi = 0.f;
            Qp[n*2] = qr; Qp[n*2 + 1] = qi;
            #pragma unroll
            for (int j = 1; j < 24; ++j) {
                float nr = qr*a16r - qi*a16i;
                float ni = qr*a16i + qi*a16r;
                qr = nr; qi = ni;
                Qp[j*68 + n*2] = qr; Qp[j*68 + n*2 + 1] = qi;
            }
            Cp[n*2] = cr; Cp[n*2 + 1] = ci;
        }
        __syncthreads();

        if (tid < TM2) {
            const int tau = tid, ii = tau & 15, jj = tau >> 4;
            const float* Pr = Pp + ii*68;
            const float* Qr = Qp + jj*68;
            float aR = 0.f, aI = 0.f;
            #pragma unroll 4
            for (int n = 0; n < 32; n += 2) {
                f32x4 p = *(const f32x4*)(Pr + 2*n);
                f32x4 q = *(const f32x4*)(Qr + 2*n);
                f32x4 c = *(const f32x4*)(Cp + 2*n);
                float w0r = p[0]*q[0] - p[1]*q[1];
                float w0i = p[0]*q[1] + p[1]*q[0];
                aR = fmaf(c[0], w0r, aR); aR = fmaf(-c[1], w0i, aR);
                aI = fmaf(c[0], w0i, aI); aI = fmaf( c[1], w0r, aI);
                float w1r = p[2]*q[2] - p[3]*q[3];
                float w1i = p[2]*q[3] + p[3]*q[2];
                aR = fmaf(c[2], w1r, aR); aR = fmaf(-c[3], w1i, aR);
                aI = fmaf(c[2], w1i, aI); aI = fmaf( c[3], w1r, aI);
            }
            hRe[tau] = aR;
            if (tau & 1) hImO[tau >> 1] = aI;
            else         hImE[tau >> 1] = aI;
        }
        __syncthreads();

        unsigned short* kd = kbf + (size_t)d*KBF_SH;
        {
            const int pt = tid & 1;
            const int g  = tid >> 1;
            const float* tb = pt ? ctL1 : ctL0;
            const float* hb = pt ? hImE : hImO;

            float acc0 = 0.f, acc1 = 0.f, acc2 = 0.f, acc3 = 0.f;
            int qb = 4*g + 192;
            f32x4 Wlo = *(const f32x4*)(tb + qb);
            f32x4 Whi = *(const f32x4*)(tb + qb + 4);

            #pragma unroll 4
            for (int R = 0; R < 48; ++R) {
                f32x4 hv = *(const f32x4*)(hb + 4*R);
                f32x4 Wn = *(const f32x4*)(tb + qb - 4);
                acc0 = fmaf(Wlo[3], hv[0], acc0); acc1 = fmaf(Whi[0], hv[0], acc1);
                acc2 = fmaf(Whi[1], hv[0], acc2); acc3 = fmaf(Whi[2], hv[0], acc3);
                acc0 = fmaf(Wlo[2], hv[1], acc0); acc1 = fmaf(Wlo[3], hv[1], acc1);
                acc2 = fmaf(Whi[0], hv[1], acc2); acc3 = fmaf(Whi[1], hv[1], acc3);
                acc0 = fmaf(Wlo[1], hv[2], acc0); acc1 = fmaf(Wlo[2], hv[2], acc1);
                acc2 = fmaf(Wlo[3], hv[2], acc2); acc3 = fmaf(Whi[0], hv[2], acc3);
                acc0 = fmaf(Wlo[0], hv[3], acc0); acc1 = fmaf(Wlo[1], hv[3], acc1);
                acc2 = fmaf(Wlo[2], hv[3], acc2); acc3 = fmaf(Wlo[3], hv[3], acc3);
                Whi = Wlo; Wlo = Wn; qb -= 4;
            }

            float accs[4] = {acc0, acc1, acc2, acc3};
            #pragma unroll
            for (int e = 0; e < 4; ++e) {
                int t = 8*g + 2*e + pt;
                float base = (t < TM2) ? hRe[t] : 0.f;
                float kv = base - accs[e] * (1.0f/(float)LSEQ);
                __hip_bfloat16 hbv = __float2bfloat16(kv);
                kd[1056 + t] = *(unsigned short*)&hbv;
            }
        }
        if (tid < 132) *(u32x4*)((unsigned char*)kd + tid*16) = (u32x4){0,0,0,0};
        if (tid < 162) *(u32x4*)((unsigned char*)kd + 6208 + tid*16) = (u32x4){0,0,0,0};
    }
}

// ============================================================ mfma kernel
#define MF(a, b, c) __builtin_amdgcn_mfma_f32_16x16x32_bf16((a), (b), (c), 0, 0, 0)

// B-ring of 4, loaded 2 steps ahead (step s's B lives in Bb[s&3], written at
// body s-2). A-ring of 8 as verified in R9/R10 (slot refilled at body X-1,
// first consumed at body X's LAST MFMA -> ~2-body latency slack for both).
#define BODY(P) do {                                                        \
    const short8 bcur = Bb[(P) & 3];                                        \
    Bb[((P)+2) & 3] = *(const short8*)(sm + aBn);                           \
    acc[7] = MF(A[((P)+1) & 7], bcur, acc[7]);                              \
    A[((P)+1) & 7] = *(const short8*)(sm + aAn);                            \
    aAn += 64; aBn += 64;                                                   \
    acc[6] = MF(A[((P)+2) & 7], bcur, acc[6]);                              \
    acc[5] = MF(A[((P)+3) & 7], bcur, acc[5]);                              \
    acc[4] = MF(A[((P)+4) & 7], bcur, acc[4]);                              \
    acc[3] = MF(A[((P)+5) & 7], bcur, acc[3]);                              \
    acc[2] = MF(A[((P)+6) & 7], bcur, acc[2]);                              \
    acc[1] = MF(A[((P)+7) & 7], bcur, acc[1]);                              \
    acc[0] = MF(A[(P) & 7],     bcur, acc[0]);                              \
} while (0)

__global__ __launch_bounds__(512, 1) void s4d_mfma9(
    const unsigned short* __restrict__ uimg, const unsigned short* __restrict__ kbf,
    const float* __restrict__ Dvec, float* __restrict__ yT)
{
    extern __shared__ __align__(16) unsigned char sm[];
    const int tid = threadIdx.x;
    const int Bk  = blockIdx.x;
    const int d   = ((Bk & 7) << 5) | (Bk >> 3);   // XCD-swizzle

    // ---- stage u (2120 u32x4) + kbf (550 u32x4) via regs
    const u32x4* gu = (const u32x4*)(uimg + (size_t)d*U3SH);
    const u32x4* gk = (const u32x4*)(kbf + (size_t)d*KBF_SH);
    u32x4 stg[5], kst[2];
    #pragma unroll
    for (int r = 0; r < 5; ++r) {
        int i = tid + 512*r;
        if (i < U3SH/8) stg[r] = gu[i];
    }
    #pragma unroll
    for (int r = 0; r < 2; ++r) {
        int i = tid + 512*r;
        if (i < KBF_SH/8) kst[r] = gk[i];
    }
    #pragma unroll
    for (int r = 0; r < 5; ++r) {
        int i = tid + 512*r;
        if (i < U3SH/8) *(u32x4*)(sm + i*16) = stg[r];
    }
    #pragma unroll
    for (int r = 0; r < 2; ++r) {
        int i = tid + 512*r;
        if (i < KBF_SH/8) *(u32x4*)(sm + OFF_K + i*16) = kst[r];
    }
    __syncthreads();

    // ---- expand: slots 1..7 from slot0 (verified R9/R10)
    {
        const unsigned short* s0p = (const unsigned short*)(sm + OFF_K);
        for (int i = tid; i < 548; i += 512) {
            int z0 = i*8;
            u32x4 va = *(const u32x4*)(s0p + z0);
            u32x4 vb = *(const u32x4*)(s0p + z0 + 8);
            unsigned src[8] = { va[0], va[1], va[2], va[3],
                                vb[0], vb[1], vb[2], vb[3] };
            #pragma unroll
            for (int c = 1; c < 8; ++c) {
                u32x4 w;
                if ((c & 1) == 0) {
                    int q = c >> 1;
                    w = (u32x4){ src[q], src[q+1], src[q+2], src[q+3] };
                } else {
                    int q = (c - 1) >> 1;
                    w = (u32x4){ (src[q]   >> 16) | (src[q+1] << 16),
                                 (src[q+1] >> 16) | (src[q+2] << 16),
                                 (src[q+2] >> 16) | (src[q+3] << 16),
                                 (src[q+3] >> 16) | (src[q+4] << 16) };
                }
                *(u32x4*)(sm + OFF_K + c*KSLOT_STR + z0*2) = w;
            }
        }
    }
    __syncthreads();

    // ---- main loop (verified R9/R10 addressing; B-ring deepened to 4)
    const int lane = tid & 63, wv = tid >> 6;
    const int h    = lane >> 4;
    const int col  = lane & 15;
    const int t0w  = wv << 8;

    const int cA   = (7 - col) & 7;
    const int bA0  = OFF_K + cA*KSLOT_STR + 2*(2047 + 8*h - col - cA - t0w);
    const int laneB3 = (col & 7)*(U3STR*2) + 64 + 16*h + 32*(col >> 3);

    const float dv = Dvec[d];
    f32x4 acc[8];
    #pragma unroll
    for (int j = 0; j < 8; ++j) acc[j] = (f32x4){dv, dv, dv, dv};

    short8 A[8], Bb[4];
    #pragma unroll
    for (int w = 0; w < 8; ++w)
        A[w] = *(const short8*)(sm + bA0 - 64*((8 - w) & 7));
    Bb[0] = *(const short8*)(sm + laneB3 - 64);   // step 0
    Bb[1] = *(const short8*)(sm + laneB3);        // step 1

    int aAn = bA0 + 64;
    int aBn = laneB3 + 64;                        // next load: step 2

    BODY(0);
    for (int o = 0; o < 8; ++o) {
        BODY(1); BODY(2); BODY(3); BODY(4);
        BODY(5); BODY(6); BODY(7); BODY(0);
    }

    // ---- epilogue: f32x4 to yT[d][b][t]
    {
        const int b    = col & 7;
        const int hi16 = (col >> 3) << 4;
        float* yb = yT + (size_t)d*(8*LSEQ) + (size_t)b*LSEQ;
        #pragma unroll
        for (int j = 0; j < 8; ++j) {
            int trow = t0w + 32*j + hi16 + 4*h;
            *(f32x4*)(yb + trow) = acc[j];
        }
    }
}

// ============================================================ yT -> out transpose (64-t tiles)
__global__ __launch_bounds__(256) void s4d_ytr(const float* __restrict__ yT,
                                               float* __restrict__ out)
{
    extern __shared__ float tr2[];                // [64][260]
    const int tid = threadIdx.x;
    const int t0  = blockIdx.x * 64;
    const int b   = blockIdx.y;

    // pass 1: 16-lane groups read one d's 256B run (fully coalesced lines)
    const int g = tid >> 4, i = tid & 15;
    #pragma unroll
    for (int dp = 0; dp < 16; ++dp) {
        int dd = dp*16 + g;
        f32x4 v = *(const f32x4*)(yT + (size_t)dd*(8*LSEQ) + (size_t)b*LSEQ + t0 + i*4);
        tr2[(i*4+0)*260 + dd] = v[0];
        tr2[(i*4+1)*260 + dd] = v[1];
        tr2[(i*4+2)*260 + dd] = v[2];
        tr2[(i*4+3)*260 + dd] = v[3];
    }
    __syncthreads();
    // pass 2: 1KB coalesced rows to out
    const int d4 = (tid & 63)*4, ttB = tid >> 6;
    #pragma unroll
    for (int s = 0; s < 16; ++s) {
        int tt = s*4 + ttB;
        f32x4 w = *(const f32x4*)(tr2 + tt*260 + d4);
        *(f32x4*)(out + ((size_t)b*LSEQ + t0 + tt)*DMODEL + d4) = w;
    }
}

// ============================================================ fallback (R1, verified)
__global__ __launch_bounds__(256) void s4d_build_k(
    const float* __restrict__ A_real, const float* __restrict__ A_imag,
    const float* __restrict__ C_real, const float* __restrict__ C_imag,
    float* __restrict__ kT)
{
    __shared__ float hRe[TMAX], hIm[TMAX], ct[LSEQ], prm[4][NHALF];
    const int tid = threadIdx.x;
    const int d   = blockIdx.x;
    if (tid < NHALF) {
        prm[0][tid] = A_real[d*NHALF + tid];
        prm[1][tid] = A_imag[d*NHALF + tid];
        prm[2][tid] = C_real[d*NHALF + tid];
        prm[3][tid] = C_imag[d*NHALF + tid];
    }
    #pragma unroll
    for (int r = 0; r < LSEQ/256; ++r) {
        int i = tid + 256*r;
        float ang = (float)(M_PI/(2.0*(double)LSEQ)) * (float)(2*i + 1);
        float sv, cv; sincosf(ang, &sv, &cv);
        ct[i] = cv / sv;
    }
    __syncthreads();
    for (int r = 0; r < TMAX/256; ++r) {
        int tau = tid + 256*r;
        float aR = 0.f, aI = 0.f;
        for (int n = 0; n < NHALF; ++n) {
            float lr  = -expf(prm[0][n]) * 0.1f;
            float amp = expf(lr * (float)tau);
            double ph = (double)prm[1][n] * 0.1 * (double)tau;
            ph -= floor(ph * (1.0/(2.0*M_PI))) * (2.0*M_PI);
            float sv, cv; sincosf((float)ph, &sv, &cv);
            float cr = prm[2][n], ci = prm[3][n];
            aR = fmaf(amp, cr*cv - ci*sv, aR);
            aI = fmaf(amp, cr*sv + ci*cv, aI);
        }
        hRe[tau] = aR; hIm[tau] = aI;
    }
    __syncthreads();
    float base[8], hsum[8];
    #pragma unroll
    for (int r = 0; r < 8; ++r) {
        base[r] = (r < 4) ? hRe[tid + 256*r] : 0.f;
        hsum[r] = 0.f;
    }
    const int tau0 = (tid & 1) ^ 1;
    for (int tau = tau0; tau < TMAX; tau += 2) {
        float him = hIm[tau];
        #pragma unroll
        for (int r = 0; r < 8; ++r) {
            int idx = ((tid + 256*r - tau) & (2*LSEQ - 1)) >> 1;
            hsum[r] = fmaf(ct[idx], him, hsum[r]);
        }
    }
    #pragma unroll
    for (int r = 0; r < 8; ++r) {
        int t = tid + 256*r;
        kT[(t + KPAD)*DMODEL + d] = base[r] - hsum[r] * (1.0f/(float)LSEQ);
    }
    if (tid < 2*KPAD) {
        int row = (tid < KPAD) ? tid : (LSEQ + KPAD + (tid - KPAD));
        kT[row*DMODEL + d] = 0.f;
    }
}

__global__ __launch_bounds__(256) void s4d_conv(
    const float* __restrict__ u, const float* __restrict__ Dvec,
    const float* __restrict__ kT, float* __restrict__ out)
{
    const int d  = threadIdx.x;
    const int t0 = blockIdx.x * TT;
    const int b  = blockIdx.y;
    float dvv = Dvec[d];
    float acc[TT];
    #pragma unroll
    for (int i = 0; i < TT; ++i) acc[i] = dvv;
    const float* ub   = u + (size_t)b * LSEQ * DMODEL + d;
    const float* kcol = kT + d;
    int mstart = t0 - 1024; if (mstart < 0) mstart = 0;
    int mend   = t0 + 1040; if (mend > LSEQ) mend = LSEQ;
    float kreg[31];
    {
        int jpb = mstart - t0 + 1024;
        #pragma unroll
        for (int r = 0; r < 31; ++r) kreg[r] = kcol[(jpb + r)*DMODEL];
    }
    for (int m0 = mstart; m0 < mend; m0 += TT) {
        float ureg[TT];
        #pragma unroll
        for (int mm = 0; mm < TT; ++mm) ureg[mm] = ub[(m0 + mm)*DMODEL];
        float knew[TT];
        if (m0 + TT < mend) {
            int jnb = m0 - t0 + 1024 + 31;
            #pragma unroll
            for (int r = 0; r < TT; ++r) knew[r] = kcol[(jnb + r)*DMODEL];
        } else {
            #pragma unroll
            for (int r = 0; r < TT; ++r) knew[r] = 0.f;
        }
        #pragma unroll
        for (int mm = 0; mm < TT; ++mm)
            #pragma unroll
            for (int tt = 0; tt < TT; ++tt)
                acc[tt] = fmaf(ureg[mm], kreg[mm - tt + 15], acc[tt]);
        #pragma unroll
        for (int r = 0; r < 15; ++r) kreg[r] = kreg[r + 16];
        #pragma unroll
        for (int r = 0; r < 16; ++r) kreg[15 + r] = knew[r];
    }
    float* ob = out + ((size_t)b * LSEQ + t0) * DMODEL + d;
    #pragma unroll
    for (int tt = 0; tt < TT; ++tt) ob[tt*DMODEL] = acc[tt];
}

// ============================================================ launch
extern "C" void kernel_launch(void* const* d_in, const int* in_sizes, int n_in,
                              void* d_out, int out_size, void* d_ws, size_t ws_size,
                              hipStream_t stream)
{
    const float* u  = (const float*)d_in[0];
    const float* Ar = (const float*)d_in[1];
    const float* Ai = (const float*)d_in[2];
    const float* Cr = (const float*)d_in[3];
    const float* Ci = (const float*)d_in[4];
    const float* Dv = (const float*)d_in[5];
    float* out = (float*)d_out;
    int B = in_sizes[0] / (LSEQ * DMODEL);

    if (B == 8 && ws_size >= WS_NEED3) {
        unsigned short* uimg = (unsigned short*)d_ws;
        unsigned short* kbf  = uimg + KBF_OFF_SH;
        float* yT = (float*)((unsigned char*)d_ws + YT_OFF_B);
        hipFuncSetAttribute((const void*)s4d_mfma9,
                            hipFuncAttributeMaxDynamicSharedMemorySize, SMEM_F3);
        hipFuncSetAttribute((const void*)s4d_ytr,
                            hipFuncAttributeMaxDynamicSharedMemorySize, YTR_SMEM);
        s4d_prep<<<dim3(32, 16), 512, 0, stream>>>(u, Ar, Ai, Cr, Ci, uimg, kbf);
        s4d_mfma9<<<DMODEL, 512, SMEM_F3, stream>>>(uimg, kbf, Dv, yT);
        s4d_ytr<<<dim3(LSEQ/64, 8), 256, YTR_SMEM, stream>>>(yT, out);
    } else {
        float* kT = (float*)d_ws;
        s4d_build_k<<<DMODEL, 256, 0, stream>>>(Ar, Ai, Cr, Ci, kT);
        s4d_conv<<<dim3(LSEQ/TT, B), 256, 0, stream>>>(u, Dv, kT, out);
    }
}